// Round 8
// baseline (225.157 us; speedup 1.0000x reference)
//
#include <hip/hip_runtime.h>

typedef unsigned short u16;
typedef unsigned int u32;
typedef __attribute__((ext_vector_type(8))) short short8;
typedef __attribute__((ext_vector_type(4))) float f32x4;

#define MFMA16(a, b, c) __builtin_amdgcn_mfma_f32_16x16x32_bf16(a, b, c, 0, 0, 0)

// B=2, S=2048, D=1024, H=16, KVH=4, dk=64, G=4
#define SEQ 2048
#define DM 1024

__device__ __forceinline__ u16 f2bf(float f) {
  u32 u = __float_as_uint(f);
  u += 0x7fffu + ((u >> 16) & 1u);  // RNE
  return (u16)(u >> 16);
}
// RNE pack via HW packed convert (gfx950): 1 instruction (RNE, matches f2bf)
__device__ __forceinline__ u32 pack2(float a, float b) {
  u32 r;
  asm("v_cvt_pk_bf16_f32 %0, %1, %2" : "=v"(r) : "v"(a), "v"(b));
  return r;
}
__device__ __forceinline__ u32 pack2t(float a, float b) {  // truncating pack: 1 v_perm
  return __builtin_amdgcn_perm(__float_as_uint(b), __float_as_uint(a), 0x07060302u);
}
// two-register cross-lane swaps (gfx950): modify both operands in place
__device__ __forceinline__ void pswap32(u32& a, u32& b) {
  asm("v_permlane32_swap_b32 %0, %1" : "+v"(a), "+v"(b));
}
__device__ __forceinline__ void pswap16(u32& a, u32& b) {
  asm("v_permlane16_swap_b32 %0, %1" : "+v"(a), "+v"(b));
}
// async global->LDS, 16B per lane; dest = wave-uniform base + lane*16
__device__ __forceinline__ void gload16(const u16* g, u16* l) {
  __builtin_amdgcn_global_load_lds((const __attribute__((address_space(1))) u32*)g,
                                   (__attribute__((address_space(3))) u32*)l, 16, 0, 0);
}

// ---------- prep: weight transposes W[K,N] fp32 -> Wt[N,K] bf16, + query -> bf16 ----------
// flat grid: [0,4096) weight transpose (z=b>>10); [4096,5120) query fp32->bf16 (RNE)
__global__ __launch_bounds__(256) void k_prep(const float* __restrict__ Wq,
                                              const float* __restrict__ Wk,
                                              const float* __restrict__ Wv,
                                              const float* __restrict__ Wo,
                                              const float* __restrict__ query,
                                              u16* __restrict__ WqT, u16* __restrict__ WkT,
                                              u16* __restrict__ WvT, u16* __restrict__ WoT,
                                              u16* __restrict__ qact) {
  const int blk = blockIdx.x;
  const int tid = threadIdx.x;
  if (blk >= 4096) {
    // query conversion: 1024 blocks x 4096 elems (16 floats/thread)
    size_t base = (size_t)(blk - 4096) * 4096 + tid * 16;
    const float* p = query + base;
    uint4 o0, o1;
    float4 a = *(const float4*)p, b = *(const float4*)(p + 4);
    float4 c = *(const float4*)(p + 8), d = *(const float4*)(p + 12);
    o0.x = pack2(a.x, a.y); o0.y = pack2(a.z, a.w);
    o0.z = pack2(b.x, b.y); o0.w = pack2(b.z, b.w);
    o1.x = pack2(c.x, c.y); o1.y = pack2(c.z, c.w);
    o1.z = pack2(d.x, d.y); o1.w = pack2(d.z, d.w);
    *(uint4*)(qact + base) = o0;
    *(uint4*)(qact + base + 8) = o1;
    return;
  }
  const int z = blk >> 10, r = blk & 1023;
  const float* W = z == 0 ? Wq : (z == 1 ? Wk : (z == 2 ? Wv : Wo));
  u16* Wt = z == 0 ? WqT : (z == 1 ? WkT : (z == 2 ? WvT : WoT));
  const int N = (z == 1 || z == 2) ? 256 : 1024;
  const int n0 = (r & 31) * 32;
  if (n0 >= N) return;
  const int k0 = (r >> 5) * 32;
  __shared__ float tile[32][33];
  int x = tid & 31, y = tid >> 5;
#pragma unroll
  for (int i = 0; i < 4; i++)
    tile[y + i * 8][x] = W[(size_t)(k0 + y + i * 8) * N + n0 + x];
  __syncthreads();
#pragma unroll
  for (int i = 0; i < 4; i++)
    Wt[(size_t)(n0 + y + i * 8) * 1024 + k0 + x] = f2bf(tile[x][y + i * 8]);
}

// staging modes for gemm64 operands
#define MBF 0   // bf16 [row][k] via global_load_lds (pre-swizzled source chunk)
#define MF32 1  // fp32 [row][k]: reg-load float4x2 -> cvt_pk -> swizzled ds_write

// ---------- 64x128 bf16 GEMM core, double-buffered single-barrier pipeline ----------
// acc = A[64-tile(m0),K] * B[128-tile(n0),K]^T, K=1024, BK=64, 16 iters.
// LDS per buffer: [rows][64] u16, 16B chunks XOR-swizzled: chunk c of row r at c^(r&7).
// Pipeline: issue tile t+1 loads -> ds_read+MFMA tile t -> write-back reg-staged t+1 ->
// ONE barrier (drains vmcnt+lgkm a full compute phase after issue -> latency hidden).
// Waves: wm=wave>>1 picks 32-row half of A (2 mtiles), wn=wave&1 picks 64-row half of B.
template <int AM, int BM>
__device__ __forceinline__ void gemm64(const void* __restrict__ A, const void* __restrict__ B,
                                       int m0, int n0, int ldA, int ldB, u16* lA, u16* lB,
                                       f32x4 acc[2][4]) {
  const int tid = threadIdx.x;
  const int lane = tid & 63, wave = tid >> 6;
  const int l15 = lane & 15, quad = lane >> 4;
  const int wm = wave >> 1, wn = wave & 1;
  const int sr = tid >> 3, sch = tid & 7;                    // MF32: row, chunk
  const int gr = lane >> 3, gch = (lane & 7) ^ (lane >> 3);  // MBF: row-in-slab, src chunk
  f32x4 zero = {0.f, 0.f, 0.f, 0.f};
#pragma unroll
  for (int i = 0; i < 2; i++)
#pragma unroll
    for (int j = 0; j < 4; j++) acc[i][j] = zero;

  float rA[16], rB[32];  // reg staging (unused modes DCE'd); all indices static

  auto issue = [&](int k0, u16* dA, u16* dB) {
    if constexpr (AM == MBF) {
#pragma unroll
      for (int it = 0; it < 2; it++) {
        int w8 = wave * 2 + it;
        gload16((const u16*)A + (size_t)(m0 + w8 * 8 + gr) * ldA + k0 + gch * 8,
                dA + w8 * 512);
      }
    } else {
#pragma unroll
      for (int it = 0; it < 2; it++) {
        const float* p = (const float*)A + (size_t)(m0 + sr + it * 32) * ldA + k0 + sch * 8;
        float4 a = *(const float4*)p, b = *(const float4*)(p + 4);
        rA[it * 8 + 0] = a.x; rA[it * 8 + 1] = a.y; rA[it * 8 + 2] = a.z; rA[it * 8 + 3] = a.w;
        rA[it * 8 + 4] = b.x; rA[it * 8 + 5] = b.y; rA[it * 8 + 6] = b.z; rA[it * 8 + 7] = b.w;
      }
    }
    if constexpr (BM == MBF) {
#pragma unroll
      for (int it = 0; it < 4; it++) {
        int w8 = wave * 4 + it;
        gload16((const u16*)B + (size_t)(n0 + w8 * 8 + gr) * ldB + k0 + gch * 8,
                dB + w8 * 512);
      }
    } else {
#pragma unroll
      for (int it = 0; it < 4; it++) {
        const float* p = (const float*)B + (size_t)(n0 + sr + it * 32) * ldB + k0 + sch * 8;
        float4 a = *(const float4*)p, b = *(const float4*)(p + 4);
        rB[it * 8 + 0] = a.x; rB[it * 8 + 1] = a.y; rB[it * 8 + 2] = a.z; rB[it * 8 + 3] = a.w;
        rB[it * 8 + 4] = b.x; rB[it * 8 + 5] = b.y; rB[it * 8 + 6] = b.z; rB[it * 8 + 7] = b.w;
      }
    }
  };

  auto wrb = [&](u16* dA, u16* dB) {
    if constexpr (AM == MF32) {
#pragma unroll
      for (int it = 0; it < 2; it++) {
        int r = sr + it * 32;
        uint4 v;
        v.x = pack2(rA[it * 8 + 0], rA[it * 8 + 1]);
        v.y = pack2(rA[it * 8 + 2], rA[it * 8 + 3]);
        v.z = pack2(rA[it * 8 + 4], rA[it * 8 + 5]);
        v.w = pack2(rA[it * 8 + 6], rA[it * 8 + 7]);
        *(uint4*)&dA[r * 64 + ((sch ^ (r & 7)) << 3)] = v;
      }
    }
    if constexpr (BM == MF32) {
#pragma unroll
      for (int it = 0; it < 4; it++) {
        int r = sr + it * 32;
        uint4 v;
        v.x = pack2(rB[it * 8 + 0], rB[it * 8 + 1]);
        v.y = pack2(rB[it * 8 + 2], rB[it * 8 + 3]);
        v.z = pack2(rB[it * 8 + 4], rB[it * 8 + 5]);
        v.w = pack2(rB[it * 8 + 6], rB[it * 8 + 7]);
        *(uint4*)&dB[r * 64 + ((sch ^ (r & 7)) << 3)] = v;
      }
    }
  };

  // prologue: stage tile 0 into buffer 0
  issue(0, lA, lB);
  wrb(lA, lB);
  __syncthreads();

  for (int t = 0; t < 16; t++) {
    u16* cA = lA + (t & 1) * 4096;
    u16* cB = lB + (t & 1) * 8192;
    u16* nA = lA + ((t + 1) & 1) * 4096;
    u16* nB = lB + ((t + 1) & 1) * 8192;
    if (t < 15) issue((t + 1) * 64, nA, nB);  // loads in flight across compute phase
    short8 af[2][2], bfr[4][2];
#pragma unroll
    for (int i = 0; i < 2; i++)
#pragma unroll
      for (int kb = 0; kb < 2; kb++) {
        int r = wm * 32 + i * 16 + l15;
        af[i][kb] = *(const short8*)&cA[r * 64 + (((kb * 4 + quad) ^ (r & 7)) << 3)];
      }
#pragma unroll
    for (int j = 0; j < 4; j++)
#pragma unroll
      for (int kb = 0; kb < 2; kb++) {
        int r = wn * 64 + j * 16 + l15;
        bfr[j][kb] = *(const short8*)&cB[r * 64 + (((kb * 4 + quad) ^ (r & 7)) << 3)];
      }
#pragma unroll
    for (int i = 0; i < 2; i++)
#pragma unroll
      for (int j = 0; j < 4; j++) {
        acc[i][j] = MFMA16(af[i][0], bfr[j][0], acc[i][j]);
        acc[i][j] = MFMA16(af[i][1], bfr[j][1], acc[i][j]);
      }
    if (t < 15) wrb(nA, nB);  // write-late: converted regs land in next buffer
    __syncthreads();          // drains vmcnt (gloads) + lgkm (ds_writes); cur consumed
  }
}

// ---------- fused Q/K/V projection ----------
// flat grid 768 (natural mapping — panel re-readers land same-XCD via stride-32 ≡ 0 mod 8):
//   [0,512)   Q: A=WqT (MBF), B=qact bf16 (MBF)  — all-gload_lds path
//   [512,640) K: A=WkT (MBF), B=key_in fp32 (MF32)
//   [640,768) V: A=value_in fp32 (MF32), B=WvT (MBF)
__global__ __launch_bounds__(256, 3) void k_proj(
    const u16* __restrict__ qact, const float* __restrict__ key_in,
    const float* __restrict__ value_in, const u16* __restrict__ WqT,
    const u16* __restrict__ WkT, const u16* __restrict__ WvT, const float* __restrict__ bq,
    const float* __restrict__ bk, const float* __restrict__ bv, u16* __restrict__ qbf,
    float* __restrict__ outK, u16* __restrict__ kbf, float* __restrict__ outV,
    u16* __restrict__ vtb, float qscale) {
  __shared__ u16 lA[2 * 4096];
  __shared__ u16 lB[2 * 8192];
  const int idx = blockIdx.x;
  const int lane = threadIdx.x & 63, wave = threadIdx.x >> 6;
  const int l15 = lane & 15, quad = lane >> 4;
  const int wm = wave >> 1, wn = wave & 1;
  f32x4 acc[2][4];

  if (idx < 512) {
    int m0 = (idx >> 5) * 64, n0 = (idx & 31) * 128;
    gemm64<MBF, MBF>(WqT, qact, m0, n0, 1024, 1024, lA, lB, acc);
#pragma unroll
    for (int i = 0; i < 2; i++) {
      int c0 = m0 + wm * 32 + i * 16 + quad * 4;
      float4 bb = *(const float4*)(bq + c0);
#pragma unroll
      for (int j = 0; j < 4; j++) {
        int token = n0 + wn * 64 + j * 16 + l15;
        int b = token >> 11, s = token & 2047;
        float v0 = acc[i][j][0] + bb.x, v1 = acc[i][j][1] + bb.y;
        float v2 = acc[i][j][2] + bb.z, v3 = acc[i][j][3] + bb.w;
        int d = c0 & 63, h = c0 >> 6;
        uint2 o;
        o.x = pack2(v0 * qscale, v1 * qscale);
        o.y = pack2(v2 * qscale, v3 * qscale);
        *(uint2*)(qbf + (((size_t)(b * 16 + h) * SEQ + s) << 6) + d) = o;
      }
    }
  } else if (idx < 640) {
    int i2 = idx - 512;
    int m0 = (i2 >> 5) * 64, n0 = (i2 & 31) * 128;
    gemm64<MBF, MF32>(WkT, key_in, m0, n0, 1024, 1024, lA, lB, acc);
#pragma unroll
    for (int i = 0; i < 2; i++) {
      int c0 = m0 + wm * 32 + i * 16 + quad * 4;
      float4 bb = *(const float4*)(bk + c0);
#pragma unroll
      for (int j = 0; j < 4; j++) {
        int token = n0 + wn * 64 + j * 16 + l15;
        int b = token >> 11, s = token & 2047;
        float v0 = acc[i][j][0] + bb.x, v1 = acc[i][j][1] + bb.y;
        float v2 = acc[i][j][2] + bb.z, v3 = acc[i][j][3] + bb.w;
        int d = c0 & 63, kvh = c0 >> 6;
        size_t ix = (((size_t)(b * 4 + kvh) * SEQ + s) << 6) + d;
        float4 vv = {v0, v1, v2, v3};
        *(float4*)(outK + ix) = vv;
        uint2 o;
        o.x = pack2(v0, v1);
        o.y = pack2(v2, v3);
        *(uint2*)(kbf + ix) = o;
      }
    }
  } else {
    int i2 = idx - 640;
    int m0 = (i2 >> 1) * 64, n0 = (i2 & 1) * 128;
    gemm64<MF32, MBF>(value_in, WvT, m0, n0, 1024, 1024, lA, lB, acc);
#pragma unroll
    for (int i = 0; i < 2; i++) {
      int r0 = m0 + wm * 32 + i * 16 + quad * 4;  // token, 4-aligned
      int b = r0 >> 11, s0 = r0 & 2047;
#pragma unroll
      for (int j = 0; j < 4; j++) {
        int col = n0 + wn * 64 + j * 16 + l15;
        int kvh = col >> 6, d = col & 63;
        float bv_ = bv[col];
        float v0 = acc[i][j][0] + bv_, v1 = acc[i][j][1] + bv_;
        float v2 = acc[i][j][2] + bv_, v3 = acc[i][j][3] + bv_;
        size_t base = (((size_t)(b * 4 + kvh) * SEQ + s0) << 6) + d;
        outV[base] = v0;
        outV[base + 64] = v1;
        outV[base + 128] = v2;
        outV[base + 192] = v3;
        uint2 o;
        o.x = pack2(v0, v1);
        o.y = pack2(v2, v3);
        *(uint2*)(vtb + ((size_t)(b * 4 + kvh) * 64 + d) * SEQ + s0) = o;  // V^T
      }
    }
  }
}

// ---------- output projection: A=WoT bf16 (MBF), B=ctxb bf16 (MBF) ----------
__global__ __launch_bounds__(256, 3) void k_out(const u16* __restrict__ ctxb,
                                                const u16* __restrict__ WoT,
                                                const float* __restrict__ bo,
                                                float* __restrict__ out) {
  __shared__ u16 lA[2 * 4096];
  __shared__ u16 lB[2 * 8192];
  const int idx = blockIdx.x;
  const int m0 = (idx >> 5) * 64, n0 = (idx & 31) * 128;
  const int lane = threadIdx.x & 63, wave = threadIdx.x >> 6;
  const int l15 = lane & 15, quad = lane >> 4;
  const int wm = wave >> 1, wn = wave & 1;
  f32x4 acc[2][4];
  gemm64<MBF, MBF>(WoT, ctxb, m0, n0, 1024, 1024, lA, lB, acc);
#pragma unroll
  for (int i = 0; i < 2; i++) {
    int c0 = m0 + wm * 32 + i * 16 + quad * 4;
    float4 bb = *(const float4*)(bo + c0);
#pragma unroll
    for (int j = 0; j < 4; j++) {
      int token = n0 + wn * 64 + j * 16 + l15;
      float4 vv = {acc[i][j][0] + bb.x, acc[i][j][1] + bb.y, acc[i][j][2] + bb.z,
                   acc[i][j][3] + bb.w};
      *(float4*)(out + (size_t)token * DM + c0) = vv;
    }
  }
}

// ---------- flash attention: d-split, register-resident P, dbuf 64-key segments ----------
// grid (S/128, B*H*2): blockIdx.y = bh*2 + dh; each block computes O columns
// d in [dh*32, dh*32+32) for 128 q rows (4 waves x 32 q, 2 groups of 16).
// QK^T + softmax recomputed per d-half (registers only, math order per output
// UNCHANGED -> bit-identical results); V staged only for this half's 32 d rows.
// 24KB LDS + ~96 VGPR -> 4 blocks/CU at grid 1024 (was 2) -> cross-wave overlap
// of the serial QK->exp2->PV chain.  P routed in registers (cvt + permlane swaps).
__global__ __launch_bounds__(256, 4) void k_flash(const u16* __restrict__ Qh,
                                                  const u16* __restrict__ Kb,
                                                  const u16* __restrict__ Vt,
                                                  u16* __restrict__ ctx) {
  __shared__ u16 lK[2][64 * 64];  // [key][d], 8 chunks/row, chunk' = ch ^ (row&7)
  __shared__ u16 lV[2][32 * 64];  // [d_local][key], 8 chunks/row, chunk' = ch ^ (row&7)
  const int tid = threadIdx.x;
  const int lane = tid & 63, wave = tid >> 6;
  const int l15 = lane & 15, quad = lane >> 4;
  const int by = blockIdx.y;
  const int bh = by >> 1, dh = by & 1;
  const int b = bh >> 4, h = bh & 15, kvh = h >> 2;
  const u16* Q = Qh + (size_t)bh * SEQ * 64;
  const u16* Kp = Kb + (size_t)(b * 4 + kvh) * SEQ * 64;
  const u16* Vp = Vt + (size_t)(b * 4 + kvh) * 64 * SEQ + (size_t)(dh * 32) * SEQ;
  const int q0 = blockIdx.x * 128 + wave * 32;

  // Q B-operand fragments for both 16-q groups (n=q, k=quad*8+j), resident all pass
  short8 qf[2][2];
#pragma unroll
  for (int g = 0; g < 2; g++)
#pragma unroll
    for (int kb = 0; kb < 2; kb++)
      qf[g][kb] = *(const short8*)(Q + (size_t)(q0 + g * 16 + l15) * 64 + kb * 32 + quad * 8);

  short8 ones8;
  {
    short ov = (l15 == 0) ? (short)0x3F80 : (short)0;
    ones8 = (short8){ov, ov, ov, ov, ov, ov, ov, ov};
  }

  f32x4 zero = {0.f, 0.f, 0.f, 0.f};
  f32x4 acc[2][2];  // O^T per group: acc[g][n] rows d = dh*32 + n*16+quad*4+r, col q=l15
  f32x4 lacc[2] = {zero, zero};
#pragma unroll
  for (int g = 0; g < 2; g++)
#pragma unroll
    for (int n = 0; n < 2; n++) acc[g][n] = zero;

  const int gr3 = lane >> 3, gc7 = lane & 7;  // staging: row-in-slab, chunk

  // stage one 64-key segment (8KB K + 4KB V-half) into buffer bufi
  auto stage = [&](int kc, int bufi) {
    u16* dK = lK[bufi];
    u16* dV = lV[bufi];
#pragma unroll
    for (int i = 0; i < 2; i++) {
      int slab = wave * 2 + i;  // 8 slabs x 8 key-rows
      gload16(Kp + (size_t)(kc + slab * 8 + gr3) * 64 + ((gc7 ^ gr3) << 3), dK + slab * 512);
    }
    {
      int row = wave * 8 + gr3;  // 32 d-rows, 4 slabs (one per wave)
      gload16(Vp + (size_t)row * SEQ + kc + ((gc7 ^ gr3) << 3), dV + wave * 512);
    }
  };

  stage(0, 0);
  __syncthreads();

  for (int t = 0; t < SEQ / 64; t++) {
    if (t < SEQ / 64 - 1) stage((t + 1) * 64, (t + 1) & 1);  // async prefetch
    const u16* cK = lK[t & 1];
    const u16* cV = lV[t & 1];

    // S^T = K.Q^T : 4 key-mtiles x 32 q; K fragments read ONCE, feed both groups
    f32x4 sc[2][4];
#pragma unroll
    for (int mt = 0; mt < 4; mt++) {
      int row = mt * 16 + l15;
      short8 kf0 = *(const short8*)&cK[row * 64 + ((quad ^ (row & 7)) << 3)];
      short8 kf1 = *(const short8*)&cK[row * 64 + (((4 + quad) ^ (row & 7)) << 3)];
#pragma unroll
      for (int g = 0; g < 2; g++) {
        f32x4 t0 = MFMA16(kf0, qf[g][0], zero);
        sc[g][mt] = MFMA16(kf1, qf[g][1], t0);
      }
    }
#pragma unroll
    for (int g = 0; g < 2; g++)
#pragma unroll
      for (int mt = 0; mt < 4; mt++)
#pragma unroll
        for (int r = 0; r < 4; r++) sc[g][mt][r] = __builtin_amdgcn_exp2f(sc[g][mt][r]);

    // PV: P routed in registers via cvt + permlane swaps; O^T += V^T.P^T ; l += ones.P^T
#pragma unroll
    for (int kbp = 0; kbp < 2; kbp++) {
      short8 pf[2];
#pragma unroll
      for (int g = 0; g < 2; g++) {
        u32 U0 = pack2t(sc[g][2 * kbp][0], sc[g][2 * kbp][1]);
        u32 W0 = pack2t(sc[g][2 * kbp + 1][0], sc[g][2 * kbp + 1][1]);
        u32 U1 = pack2t(sc[g][2 * kbp][2], sc[g][2 * kbp][3]);
        u32 W1 = pack2t(sc[g][2 * kbp + 1][2], sc[g][2 * kbp + 1][3]);
        pswap32(U0, W0);
        pswap16(U0, W0);
        pswap32(U1, W1);
        pswap16(U1, W1);
        u32 w[4] = {U0, U1, W0, W1};  // F0..F3
        pf[g] = *(const short8*)w;
      }
      lacc[0] = MFMA16(ones8, pf[0], lacc[0]);
      lacc[1] = MFMA16(ones8, pf[1], lacc[1]);
#pragma unroll
      for (int n = 0; n < 2; n++) {
        int row = n * 16 + l15;  // local d row (0..31)
        int chv = kbp * 4 + quad;
        short8 vf = *(const short8*)&cV[row * 64 + ((chv ^ (row & 7)) << 3)];
        acc[0][n] = MFMA16(vf, pf[0], acc[0][n]);
        acc[1][n] = MFMA16(vf, pf[1], acc[1][n]);
      }
    }
    __syncthreads();  // all waves done with cur buffer; prefetch drained (vmcnt)
  }

  // epilogue: per group, lane q = q0+g*16+l15, d = dh*32 + n*16+quad*4+{0..3}
#pragma unroll
  for (int g = 0; g < 2; g++) {
    float lq = __shfl(lacc[g][0], l15);  // l(q) lives at quad0 reg0, lane l15
    float inv = __builtin_amdgcn_rcpf(lq);
    u16* base = ctx + ((size_t)(b * SEQ + q0 + g * 16 + l15)) * DM + h * 64 + dh * 32;
#pragma unroll
    for (int n = 0; n < 2; n++) {
      uint2 o;
      o.x = pack2t(acc[g][n][0] * inv, acc[g][n][1] * inv);
      o.y = pack2t(acc[g][n][2] * inv, acc[g][n][3] * inv);
      *(uint2*)(base + n * 16 + quad * 4) = o;
    }
  }
}

extern "C" void kernel_launch(void* const* d_in, const int* in_sizes, int n_in,
                              void* d_out, int out_size, void* d_ws, size_t ws_size,
                              hipStream_t stream) {
  const float* query = (const float*)d_in[0];
  const float* key_in = (const float*)d_in[1];
  const float* value_in = (const float*)d_in[2];
  const float* Wq = (const float*)d_in[3];
  const float* bq = (const float*)d_in[4];
  const float* Wk = (const float*)d_in[5];
  const float* bk = (const float*)d_in[6];
  const float* Wv = (const float*)d_in[7];
  const float* bv = (const float*)d_in[8];
  const float* Wo = (const float*)d_in[9];
  const float* bo = (const float*)d_in[10];

  float* out = (float*)d_out;   // [B,S,DM]
  float* outK = out + 4194304;  // [B,KVH,S,64]
  float* outV = out + 5242880;  // [B,KVH,S,64]

  char* ws = (char*)d_ws;
  u16* WqT = (u16*)(ws);               // 2M   [1024,1024] bf16
  u16* WkT = (u16*)(ws + 2097152);     // 0.5M [256,1024]
  u16* WvT = (u16*)(ws + 2621440);     // 0.5M
  u16* WoT = (u16*)(ws + 3145728);     // 2M
  u16* qact = (u16*)(ws + 5242880);    // 8M  query bf16 [B*S,1024] (dead after k_proj)
  u16* ctxb = (u16*)(ws + 5242880);    // 8M  ctx bf16 [B,S,DM] — ALIASES qact
  u16* qbf = (u16*)(ws + 13631488);    // 8M  Q bf16 [B,H,S,64], pre-scaled log2e/8
  u16* kbf = (u16*)(ws + 22020096);    // 2M  K bf16 [B,KVH,S,64]
  u16* vtb = (u16*)(ws + 24117248);    // 2M  V^T bf16 [B,KVH,64,S]
  // high-water: 26,214,400 bytes (same as previous rounds)

  const float qscale = 0.125f * 1.44269504088896340736f;  // fold log2(e) -> exp2 softmax

  k_prep<<<dim3(5120), 256, 0, stream>>>(Wq, Wk, Wv, Wo, query, WqT, WkT, WvT, WoT, qact);
  k_proj<<<dim3(768), 256, 0, stream>>>(qact, key_in, value_in, WqT, WkT, WvT, bq, bk, bv,
                                        qbf, outK, kbf, outV, vtb, qscale);
  k_flash<<<dim3(16, 64), 256, 0, stream>>>(qbf, kbf, vtb, ctxb);
  k_out<<<dim3(512), 256, 0, stream>>>(ctxb, WoT, bo, out);
}

// Round 9
// 216.197 us; speedup vs baseline: 1.0414x; 1.0414x over previous
//
#include <hip/hip_runtime.h>

typedef unsigned short u16;
typedef unsigned int u32;
typedef __attribute__((ext_vector_type(8))) short short8;
typedef __attribute__((ext_vector_type(4))) float f32x4;

#define MFMA16(a, b, c) __builtin_amdgcn_mfma_f32_16x16x32_bf16(a, b, c, 0, 0, 0)

// B=2, S=2048, D=1024, H=16, KVH=4, dk=64, G=4
#define SEQ 2048
#define DM 1024

__device__ __forceinline__ u16 f2bf(float f) {
  u32 u = __float_as_uint(f);
  u += 0x7fffu + ((u >> 16) & 1u);  // RNE
  return (u16)(u >> 16);
}
// RNE pack via HW packed convert (gfx950): 1 instruction (RNE, matches f2bf)
__device__ __forceinline__ u32 pack2(float a, float b) {
  u32 r;
  asm("v_cvt_pk_bf16_f32 %0, %1, %2" : "=v"(r) : "v"(a), "v"(b));
  return r;
}
__device__ __forceinline__ u32 pack2t(float a, float b) {  // truncating pack: 1 v_perm
  return __builtin_amdgcn_perm(__float_as_uint(b), __float_as_uint(a), 0x07060302u);
}
// two-register cross-lane swaps (gfx950): modify both operands in place
__device__ __forceinline__ void pswap32(u32& a, u32& b) {
  asm("v_permlane32_swap_b32 %0, %1" : "+v"(a), "+v"(b));
}
__device__ __forceinline__ void pswap16(u32& a, u32& b) {
  asm("v_permlane16_swap_b32 %0, %1" : "+v"(a), "+v"(b));
}
// async global->LDS, 16B per lane; dest = wave-uniform base + lane*16
__device__ __forceinline__ void gload16(const u16* g, u16* l) {
  __builtin_amdgcn_global_load_lds((const __attribute__((address_space(1))) u32*)g,
                                   (__attribute__((address_space(3))) u32*)l, 16, 0, 0);
}

// ---------- prep: weight transposes W[K,N] fp32 -> Wt[N,K] bf16, + query -> bf16 ----------
// flat grid: [0,4096) weight transpose (z=b>>10); [4096,5120) query fp32->bf16 (RNE)
__global__ __launch_bounds__(256) void k_prep(const float* __restrict__ Wq,
                                              const float* __restrict__ Wk,
                                              const float* __restrict__ Wv,
                                              const float* __restrict__ Wo,
                                              const float* __restrict__ query,
                                              u16* __restrict__ WqT, u16* __restrict__ WkT,
                                              u16* __restrict__ WvT, u16* __restrict__ WoT,
                                              u16* __restrict__ qact) {
  const int blk = blockIdx.x;
  const int tid = threadIdx.x;
  if (blk >= 4096) {
    // query conversion: 1024 blocks x 4096 elems (16 floats/thread)
    size_t base = (size_t)(blk - 4096) * 4096 + tid * 16;
    const float* p = query + base;
    uint4 o0, o1;
    float4 a = *(const float4*)p, b = *(const float4*)(p + 4);
    float4 c = *(const float4*)(p + 8), d = *(const float4*)(p + 12);
    o0.x = pack2(a.x, a.y); o0.y = pack2(a.z, a.w);
    o0.z = pack2(b.x, b.y); o0.w = pack2(b.z, b.w);
    o1.x = pack2(c.x, c.y); o1.y = pack2(c.z, c.w);
    o1.z = pack2(d.x, d.y); o1.w = pack2(d.z, d.w);
    *(uint4*)(qact + base) = o0;
    *(uint4*)(qact + base + 8) = o1;
    return;
  }
  const int z = blk >> 10, r = blk & 1023;
  const float* W = z == 0 ? Wq : (z == 1 ? Wk : (z == 2 ? Wv : Wo));
  u16* Wt = z == 0 ? WqT : (z == 1 ? WkT : (z == 2 ? WvT : WoT));
  const int N = (z == 1 || z == 2) ? 256 : 1024;
  const int n0 = (r & 31) * 32;
  if (n0 >= N) return;
  const int k0 = (r >> 5) * 32;
  __shared__ float tile[32][33];
  int x = tid & 31, y = tid >> 5;
#pragma unroll
  for (int i = 0; i < 4; i++)
    tile[y + i * 8][x] = W[(size_t)(k0 + y + i * 8) * N + n0 + x];
  __syncthreads();
#pragma unroll
  for (int i = 0; i < 4; i++)
    Wt[(size_t)(n0 + y + i * 8) * 1024 + k0 + x] = f2bf(tile[x][y + i * 8]);
}

// staging modes for gemm64 operands
#define MBF 0   // bf16 [row][k] via global_load_lds (pre-swizzled source chunk)
#define MF32 1  // fp32 [row][k]: reg-load float4x2 -> cvt_pk -> swizzled ds_write

// ---------- 64x128 bf16 GEMM core, double-buffered single-barrier pipeline ----------
// acc = A[64-tile(m0),K] * B[128-tile(n0),K]^T, K=1024, BK=64, 16 iters.
// LDS per buffer: [rows][64] u16, 16B chunks XOR-swizzled: chunk c of row r at c^(r&7).
// Pipeline: issue tile t+1 loads -> ds_read+MFMA tile t -> write-back reg-staged t+1 ->
// ONE barrier (drains vmcnt+lgkm a full compute phase after issue -> latency hidden).
// Waves: wm=wave>>1 picks 32-row half of A (2 mtiles), wn=wave&1 picks 64-row half of B.
template <int AM, int BM>
__device__ __forceinline__ void gemm64(const void* __restrict__ A, const void* __restrict__ B,
                                       int m0, int n0, int ldA, int ldB, u16* lA, u16* lB,
                                       f32x4 acc[2][4]) {
  const int tid = threadIdx.x;
  const int lane = tid & 63, wave = tid >> 6;
  const int l15 = lane & 15, quad = lane >> 4;
  const int wm = wave >> 1, wn = wave & 1;
  const int sr = tid >> 3, sch = tid & 7;                    // MF32: row, chunk
  const int gr = lane >> 3, gch = (lane & 7) ^ (lane >> 3);  // MBF: row-in-slab, src chunk
  f32x4 zero = {0.f, 0.f, 0.f, 0.f};
#pragma unroll
  for (int i = 0; i < 2; i++)
#pragma unroll
    for (int j = 0; j < 4; j++) acc[i][j] = zero;

  float rA[16], rB[32];  // reg staging (unused modes DCE'd); all indices static

  auto issue = [&](int k0, u16* dA, u16* dB) {
    if constexpr (AM == MBF) {
#pragma unroll
      for (int it = 0; it < 2; it++) {
        int w8 = wave * 2 + it;
        gload16((const u16*)A + (size_t)(m0 + w8 * 8 + gr) * ldA + k0 + gch * 8,
                dA + w8 * 512);
      }
    } else {
#pragma unroll
      for (int it = 0; it < 2; it++) {
        const float* p = (const float*)A + (size_t)(m0 + sr + it * 32) * ldA + k0 + sch * 8;
        float4 a = *(const float4*)p, b = *(const float4*)(p + 4);
        rA[it * 8 + 0] = a.x; rA[it * 8 + 1] = a.y; rA[it * 8 + 2] = a.z; rA[it * 8 + 3] = a.w;
        rA[it * 8 + 4] = b.x; rA[it * 8 + 5] = b.y; rA[it * 8 + 6] = b.z; rA[it * 8 + 7] = b.w;
      }
    }
    if constexpr (BM == MBF) {
#pragma unroll
      for (int it = 0; it < 4; it++) {
        int w8 = wave * 4 + it;
        gload16((const u16*)B + (size_t)(n0 + w8 * 8 + gr) * ldB + k0 + gch * 8,
                dB + w8 * 512);
      }
    } else {
#pragma unroll
      for (int it = 0; it < 4; it++) {
        const float* p = (const float*)B + (size_t)(n0 + sr + it * 32) * ldB + k0 + sch * 8;
        float4 a = *(const float4*)p, b = *(const float4*)(p + 4);
        rB[it * 8 + 0] = a.x; rB[it * 8 + 1] = a.y; rB[it * 8 + 2] = a.z; rB[it * 8 + 3] = a.w;
        rB[it * 8 + 4] = b.x; rB[it * 8 + 5] = b.y; rB[it * 8 + 6] = b.z; rB[it * 8 + 7] = b.w;
      }
    }
  };

  auto wrb = [&](u16* dA, u16* dB) {
    if constexpr (AM == MF32) {
#pragma unroll
      for (int it = 0; it < 2; it++) {
        int r = sr + it * 32;
        uint4 v;
        v.x = pack2(rA[it * 8 + 0], rA[it * 8 + 1]);
        v.y = pack2(rA[it * 8 + 2], rA[it * 8 + 3]);
        v.z = pack2(rA[it * 8 + 4], rA[it * 8 + 5]);
        v.w = pack2(rA[it * 8 + 6], rA[it * 8 + 7]);
        *(uint4*)&dA[r * 64 + ((sch ^ (r & 7)) << 3)] = v;
      }
    }
    if constexpr (BM == MF32) {
#pragma unroll
      for (int it = 0; it < 4; it++) {
        int r = sr + it * 32;
        uint4 v;
        v.x = pack2(rB[it * 8 + 0], rB[it * 8 + 1]);
        v.y = pack2(rB[it * 8 + 2], rB[it * 8 + 3]);
        v.z = pack2(rB[it * 8 + 4], rB[it * 8 + 5]);
        v.w = pack2(rB[it * 8 + 6], rB[it * 8 + 7]);
        *(uint4*)&dB[r * 64 + ((sch ^ (r & 7)) << 3)] = v;
      }
    }
  };

  // prologue: stage tile 0 into buffer 0
  issue(0, lA, lB);
  wrb(lA, lB);
  __syncthreads();

  for (int t = 0; t < 16; t++) {
    u16* cA = lA + (t & 1) * 4096;
    u16* cB = lB + (t & 1) * 8192;
    u16* nA = lA + ((t + 1) & 1) * 4096;
    u16* nB = lB + ((t + 1) & 1) * 8192;
    if (t < 15) issue((t + 1) * 64, nA, nB);  // loads in flight across compute phase
    short8 af[2][2], bfr[4][2];
#pragma unroll
    for (int i = 0; i < 2; i++)
#pragma unroll
      for (int kb = 0; kb < 2; kb++) {
        int r = wm * 32 + i * 16 + l15;
        af[i][kb] = *(const short8*)&cA[r * 64 + (((kb * 4 + quad) ^ (r & 7)) << 3)];
      }
#pragma unroll
    for (int j = 0; j < 4; j++)
#pragma unroll
      for (int kb = 0; kb < 2; kb++) {
        int r = wn * 64 + j * 16 + l15;
        bfr[j][kb] = *(const short8*)&cB[r * 64 + (((kb * 4 + quad) ^ (r & 7)) << 3)];
      }
#pragma unroll
    for (int i = 0; i < 2; i++)
#pragma unroll
      for (int j = 0; j < 4; j++) {
        acc[i][j] = MFMA16(af[i][0], bfr[j][0], acc[i][j]);
        acc[i][j] = MFMA16(af[i][1], bfr[j][1], acc[i][j]);
      }
    if (t < 15) wrb(nA, nB);  // write-late: converted regs land in next buffer
    __syncthreads();          // drains vmcnt (gloads) + lgkm (ds_writes); cur consumed
  }
}

// ---------- Q projection: A=WqT (MBF), B=qact (MBF), 512 blocks ----------
// XCD-chunked panel-major (512 = 8*64): XCD r owns logical [64r, 64r+64) =
// 4 token-panels x 16 col-tiles -> concurrent L2 set = WqT 2MB + 4x256KB = 3MB <= 4MB.
__global__ __launch_bounds__(256, 3) void k_projq(const u16* __restrict__ qact,
                                                  const u16* __restrict__ WqT,
                                                  const float* __restrict__ bq,
                                                  u16* __restrict__ qbf, float qscale) {
  __shared__ u16 lA[2 * 4096];
  __shared__ u16 lB[2 * 8192];
  const int bid = blockIdx.x;
  const int qi = (bid & 7) * 64 + (bid >> 3);  // bijective XCD chunk
  const int m0 = (qi & 15) * 64, n0 = (qi >> 4) * 128;
  const int lane = threadIdx.x & 63, wave = threadIdx.x >> 6;
  const int l15 = lane & 15, quad = lane >> 4;
  const int wm = wave >> 1, wn = wave & 1;
  f32x4 acc[2][4];
  gemm64<MBF, MBF>(WqT, qact, m0, n0, 1024, 1024, lA, lB, acc);
#pragma unroll
  for (int i = 0; i < 2; i++) {
    int c0 = m0 + wm * 32 + i * 16 + quad * 4;
    float4 bb = *(const float4*)(bq + c0);
#pragma unroll
    for (int j = 0; j < 4; j++) {
      int token = n0 + wn * 64 + j * 16 + l15;
      int b = token >> 11, s = token & 2047;
      float v0 = acc[i][j][0] + bb.x, v1 = acc[i][j][1] + bb.y;
      float v2 = acc[i][j][2] + bb.z, v3 = acc[i][j][3] + bb.w;
      int d = c0 & 63, h = c0 >> 6;
      uint2 o;
      o.x = pack2(v0 * qscale, v1 * qscale);
      o.y = pack2(v2 * qscale, v3 * qscale);
      *(uint2*)(qbf + (((size_t)(b * 16 + h) * SEQ + s) << 6) + d) = o;
    }
  }
}

// ---------- K/V projection: 256 blocks, XCD-chunked (256 = 8*32) ----------
// XCD r owns o in [0,32): o<16 -> K block ki=16r+o (4 panels x 4 col-tiles);
// o>=16 -> V block vi=16r+(o-16) (8 token-tiles x 2 col-tiles, pairs adjacent).
__global__ __launch_bounds__(256, 3) void k_projkv(
    const float* __restrict__ key_in, const float* __restrict__ value_in,
    const u16* __restrict__ WkT, const u16* __restrict__ WvT, const float* __restrict__ bk,
    const float* __restrict__ bv, float* __restrict__ outK, u16* __restrict__ kbf,
    float* __restrict__ outV, u16* __restrict__ vtb) {
  __shared__ u16 lA[2 * 4096];
  __shared__ u16 lB[2 * 8192];
  const int bid = blockIdx.x;
  const int r = bid & 7, o = bid >> 3;
  const int lane = threadIdx.x & 63, wave = threadIdx.x >> 6;
  const int l15 = lane & 15, quad = lane >> 4;
  const int wm = wave >> 1, wn = wave & 1;
  f32x4 acc[2][4];

  if (o < 16) {
    int ki = r * 16 + o;
    int m0 = (ki & 3) * 64, n0 = (ki >> 2) * 128;
    gemm64<MBF, MF32>(WkT, key_in, m0, n0, 1024, 1024, lA, lB, acc);
#pragma unroll
    for (int i = 0; i < 2; i++) {
      int c0 = m0 + wm * 32 + i * 16 + quad * 4;
      float4 bb = *(const float4*)(bk + c0);
#pragma unroll
      for (int j = 0; j < 4; j++) {
        int token = n0 + wn * 64 + j * 16 + l15;
        int b = token >> 11, s = token & 2047;
        float v0 = acc[i][j][0] + bb.x, v1 = acc[i][j][1] + bb.y;
        float v2 = acc[i][j][2] + bb.z, v3 = acc[i][j][3] + bb.w;
        int d = c0 & 63, kvh = c0 >> 6;
        size_t ix = (((size_t)(b * 4 + kvh) * SEQ + s) << 6) + d;
        float4 vv = {v0, v1, v2, v3};
        *(float4*)(outK + ix) = vv;
        uint2 ob;
        ob.x = pack2(v0, v1);
        ob.y = pack2(v2, v3);
        *(uint2*)(kbf + ix) = ob;
      }
    }
  } else {
    int vi = r * 16 + (o - 16);
    int m0 = (vi >> 1) * 64, n0 = (vi & 1) * 128;
    gemm64<MF32, MBF>(value_in, WvT, m0, n0, 1024, 1024, lA, lB, acc);
#pragma unroll
    for (int i = 0; i < 2; i++) {
      int r0 = m0 + wm * 32 + i * 16 + quad * 4;  // token, 4-aligned
      int b = r0 >> 11, s0 = r0 & 2047;
#pragma unroll
      for (int j = 0; j < 4; j++) {
        int col = n0 + wn * 64 + j * 16 + l15;
        int kvh = col >> 6, d = col & 63;
        float bv_ = bv[col];
        float v0 = acc[i][j][0] + bv_, v1 = acc[i][j][1] + bv_;
        float v2 = acc[i][j][2] + bv_, v3 = acc[i][j][3] + bv_;
        size_t base = (((size_t)(b * 4 + kvh) * SEQ + s0) << 6) + d;
        outV[base] = v0;
        outV[base + 64] = v1;
        outV[base + 128] = v2;
        outV[base + 192] = v3;
        uint2 ob;
        ob.x = pack2(v0, v1);
        ob.y = pack2(v2, v3);
        *(uint2*)(vtb + ((size_t)(b * 4 + kvh) * 64 + d) * SEQ + s0) = ob;  // V^T
      }
    }
  }
}

// ---------- output projection: A=WoT (MBF), B=ctxb (MBF), 512 blocks ----------
// XCD-chunked panel-major (512 = 8*64): concurrent L2 set = WoT 2MB + 4x256KB = 3MB.
__global__ __launch_bounds__(256, 3) void k_out(const u16* __restrict__ ctxb,
                                                const u16* __restrict__ WoT,
                                                const float* __restrict__ bo,
                                                float* __restrict__ out) {
  __shared__ u16 lA[2 * 4096];
  __shared__ u16 lB[2 * 8192];
  const int bid = blockIdx.x;
  const int oi = (bid & 7) * 64 + (bid >> 3);  // bijective XCD chunk
  const int m0 = (oi & 15) * 64, n0 = (oi >> 4) * 128;
  const int lane = threadIdx.x & 63, wave = threadIdx.x >> 6;
  const int l15 = lane & 15, quad = lane >> 4;
  const int wm = wave >> 1, wn = wave & 1;
  f32x4 acc[2][4];
  gemm64<MBF, MBF>(WoT, ctxb, m0, n0, 1024, 1024, lA, lB, acc);
#pragma unroll
  for (int i = 0; i < 2; i++) {
    int c0 = m0 + wm * 32 + i * 16 + quad * 4;
    float4 bb = *(const float4*)(bo + c0);
#pragma unroll
    for (int j = 0; j < 4; j++) {
      int token = n0 + wn * 64 + j * 16 + l15;
      float4 vv = {acc[i][j][0] + bb.x, acc[i][j][1] + bb.y, acc[i][j][2] + bb.z,
                   acc[i][j][3] + bb.w};
      *(float4*)(out + (size_t)token * DM + c0) = vv;
    }
  }
}

// ---------- flash attention: register-resident P, double-buffered K/V staging ----------
// (exact round-4/round-7 version — 46.8-48.5us measured, kept as control)
__global__ __launch_bounds__(256, 2) void k_flash(const u16* __restrict__ Qh,
                                                  const u16* __restrict__ Kb,
                                                  const u16* __restrict__ Vt,
                                                  u16* __restrict__ ctx) {
  __shared__ u16 lK[2][128 * 64];  // [key][d], 8 chunks/row, chunk' = ch ^ (row&7)
  __shared__ u16 lV[2][64 * 128];  // [d][key], 16 chunks/row, chunk' = ch ^ (row&15)
  const int tid = threadIdx.x;
  const int lane = tid & 63, wave = tid >> 6;
  const int l15 = lane & 15, quad = lane >> 4;
  const int bh = blockIdx.y;
  const int b = bh >> 4, h = bh & 15, kvh = h >> 2;
  const u16* Q = Qh + (size_t)bh * SEQ * 64;
  const u16* Kp = Kb + (size_t)(b * 4 + kvh) * SEQ * 64;
  const u16* Vp = Vt + (size_t)(b * 4 + kvh) * 64 * SEQ;
  const int q0 = blockIdx.x * 128 + wave * 32;

  short8 qf[2][2];
#pragma unroll
  for (int g = 0; g < 2; g++)
#pragma unroll
    for (int kb = 0; kb < 2; kb++)
      qf[g][kb] = *(const short8*)(Q + (size_t)(q0 + g * 16 + l15) * 64 + kb * 32 + quad * 8);

  short8 ones8;
  {
    short ov = (l15 == 0) ? (short)0x3F80 : (short)0;
    ones8 = (short8){ov, ov, ov, ov, ov, ov, ov, ov};
  }

  f32x4 zero = {0.f, 0.f, 0.f, 0.f};
  f32x4 acc[2][4];  // O^T per group: acc[g][n] rows d=n*16+quad*4+r, col q=l15
  f32x4 lacc[2] = {zero, zero};
#pragma unroll
  for (int g = 0; g < 2; g++)
#pragma unroll
    for (int n = 0; n < 4; n++) acc[g][n] = zero;

  const int gr3 = lane >> 3, gc7 = lane & 7;    // K staging: row-in-slab, chunk
  const int gr4 = lane >> 4, gc15 = lane & 15;  // V staging

  auto stage = [&](int kc, int bufi) {
    u16* dK = lK[bufi];
    u16* dV = lV[bufi];
#pragma unroll
    for (int i = 0; i < 4; i++) {
      int slab = wave * 4 + i;
      gload16(Kp + (size_t)(kc + slab * 8 + gr3) * 64 + ((gc7 ^ gr3) << 3), dK + slab * 512);
    }
#pragma unroll
    for (int i = 0; i < 4; i++) {
      int slab = wave * 4 + i;
      int row = slab * 4 + gr4;
      gload16(Vp + (size_t)row * SEQ + kc + ((gc15 ^ (row & 15)) << 3), dV + slab * 512);
    }
  };

  stage(0, 0);
  __syncthreads();

  for (int t = 0; t < SEQ / 128; t++) {
    if (t < SEQ / 128 - 1) stage((t + 1) * 128, (t + 1) & 1);  // async prefetch
    const u16* cK = lK[t & 1];
    const u16* cV = lV[t & 1];

#pragma unroll
    for (int sub = 0; sub < 2; sub++) {
      const int ks = sub * 64;
      f32x4 sc[2][4];
#pragma unroll
      for (int mt = 0; mt < 4; mt++) {
        int row = ks + mt * 16 + l15;
        short8 kf0 = *(const short8*)&cK[row * 64 + ((quad ^ (row & 7)) << 3)];
        short8 kf1 = *(const short8*)&cK[row * 64 + (((4 + quad) ^ (row & 7)) << 3)];
#pragma unroll
        for (int g = 0; g < 2; g++) {
          f32x4 t0 = MFMA16(kf0, qf[g][0], zero);
          sc[g][mt] = MFMA16(kf1, qf[g][1], t0);
        }
      }
#pragma unroll
      for (int g = 0; g < 2; g++)
#pragma unroll
        for (int mt = 0; mt < 4; mt++)
#pragma unroll
          for (int r = 0; r < 4; r++) sc[g][mt][r] = __builtin_amdgcn_exp2f(sc[g][mt][r]);

#pragma unroll
      for (int kbp = 0; kbp < 2; kbp++) {
        short8 pf[2];
#pragma unroll
        for (int g = 0; g < 2; g++) {
          u32 U0 = pack2t(sc[g][2 * kbp][0], sc[g][2 * kbp][1]);
          u32 W0 = pack2t(sc[g][2 * kbp + 1][0], sc[g][2 * kbp + 1][1]);
          u32 U1 = pack2t(sc[g][2 * kbp][2], sc[g][2 * kbp][3]);
          u32 W1 = pack2t(sc[g][2 * kbp + 1][2], sc[g][2 * kbp + 1][3]);
          pswap32(U0, W0);
          pswap16(U0, W0);
          pswap32(U1, W1);
          pswap16(U1, W1);
          u32 w[4] = {U0, U1, W0, W1};  // F0..F3
          pf[g] = *(const short8*)w;
        }
        lacc[0] = MFMA16(ones8, pf[0], lacc[0]);
        lacc[1] = MFMA16(ones8, pf[1], lacc[1]);
#pragma unroll
        for (int n = 0; n < 4; n++) {
          int row = n * 16 + l15;
          int chv = sub * 8 + kbp * 4 + quad;
          short8 vf = *(const short8*)&cV[row * 128 + ((chv ^ (row & 15)) << 3)];
          acc[0][n] = MFMA16(vf, pf[0], acc[0][n]);
          acc[1][n] = MFMA16(vf, pf[1], acc[1][n]);
        }
      }
    }
    __syncthreads();
  }

#pragma unroll
  for (int g = 0; g < 2; g++) {
    float lq = __shfl(lacc[g][0], l15);
    float inv = __builtin_amdgcn_rcpf(lq);
    u16* base = ctx + ((size_t)(b * SEQ + q0 + g * 16 + l15)) * DM + h * 64;
#pragma unroll
    for (int n = 0; n < 4; n++) {
      uint2 o;
      o.x = pack2t(acc[g][n][0] * inv, acc[g][n][1] * inv);
      o.y = pack2t(acc[g][n][2] * inv, acc[g][n][3] * inv);
      *(uint2*)(base + n * 16 + quad * 4) = o;
    }
  }
}

extern "C" void kernel_launch(void* const* d_in, const int* in_sizes, int n_in,
                              void* d_out, int out_size, void* d_ws, size_t ws_size,
                              hipStream_t stream) {
  const float* query = (const float*)d_in[0];
  const float* key_in = (const float*)d_in[1];
  const float* value_in = (const float*)d_in[2];
  const float* Wq = (const float*)d_in[3];
  const float* bq = (const float*)d_in[4];
  const float* Wk = (const float*)d_in[5];
  const float* bk = (const float*)d_in[6];
  const float* Wv = (const float*)d_in[7];
  const float* bv = (const float*)d_in[8];
  const float* Wo = (const float*)d_in[9];
  const float* bo = (const float*)d_in[10];

  float* out = (float*)d_out;   // [B,S,DM]
  float* outK = out + 4194304;  // [B,KVH,S,64]
  float* outV = out + 5242880;  // [B,KVH,S,64]

  char* ws = (char*)d_ws;
  u16* WqT = (u16*)(ws);               // 2M   [1024,1024] bf16
  u16* WkT = (u16*)(ws + 2097152);     // 0.5M [256,1024]
  u16* WvT = (u16*)(ws + 2621440);     // 0.5M
  u16* WoT = (u16*)(ws + 3145728);     // 2M
  u16* qact = (u16*)(ws + 5242880);    // 8M  query bf16 [B*S,1024] (dead after k_projq)
  u16* ctxb = (u16*)(ws + 5242880);    // 8M  ctx bf16 [B,S,DM] — ALIASES qact
  u16* qbf = (u16*)(ws + 13631488);    // 8M  Q bf16 [B,H,S,64], pre-scaled log2e/8
  u16* kbf = (u16*)(ws + 22020096);    // 2M  K bf16 [B,KVH,S,64]
  u16* vtb = (u16*)(ws + 24117248);    // 2M  V^T bf16 [B,KVH,64,S]
  // high-water: 26,214,400 bytes (same as previous rounds)

  const float qscale = 0.125f * 1.44269504088896340736f;  // fold log2(e) -> exp2 softmax

  k_prep<<<dim3(5120), 256, 0, stream>>>(Wq, Wk, Wv, Wo, query, WqT, WkT, WvT, WoT, qact);
  k_projkv<<<dim3(256), 256, 0, stream>>>(key_in, value_in, WkT, WvT, bk, bv, outK, kbf,
                                          outV, vtb);
  k_projq<<<dim3(512), 256, 0, stream>>>(qact, WqT, bq, qbf, qscale);
  k_flash<<<dim3(16, 32), 256, 0, stream>>>(qbf, kbf, vtb, ctxb);
  k_out<<<dim3(512), 256, 0, stream>>>(ctxb, WoT, bo, out);
}

// Round 10
// 208.079 us; speedup vs baseline: 1.0821x; 1.0390x over previous
//
#include <hip/hip_runtime.h>

typedef unsigned short u16;
typedef unsigned int u32;
typedef __attribute__((ext_vector_type(8))) short short8;
typedef __attribute__((ext_vector_type(4))) float f32x4;

#define MFMA16(a, b, c) __builtin_amdgcn_mfma_f32_16x16x32_bf16(a, b, c, 0, 0, 0)

// B=2, S=2048, D=1024, H=16, KVH=4, dk=64, G=4
#define SEQ 2048
#define DM 1024

__device__ __forceinline__ u16 f2bf(float f) {
  u32 u = __float_as_uint(f);
  u += 0x7fffu + ((u >> 16) & 1u);  // RNE
  return (u16)(u >> 16);
}
// RNE pack via HW packed convert (gfx950): 1 instruction (RNE, matches f2bf)
__device__ __forceinline__ u32 pack2(float a, float b) {
  u32 r;
  asm("v_cvt_pk_bf16_f32 %0, %1, %2" : "=v"(r) : "v"(a), "v"(b));
  return r;
}
__device__ __forceinline__ u32 pack2t(float a, float b) {  // truncating pack: 1 v_perm
  return __builtin_amdgcn_perm(__float_as_uint(b), __float_as_uint(a), 0x07060302u);
}
// two-register cross-lane swaps (gfx950): modify both operands in place
__device__ __forceinline__ void pswap32(u32& a, u32& b) {
  asm("v_permlane32_swap_b32 %0, %1" : "+v"(a), "+v"(b));
}
__device__ __forceinline__ void pswap16(u32& a, u32& b) {
  asm("v_permlane16_swap_b32 %0, %1" : "+v"(a), "+v"(b));
}
// async global->LDS, 16B per lane; dest = wave-uniform base + lane*16
__device__ __forceinline__ void gload16(const u16* g, u16* l) {
  __builtin_amdgcn_global_load_lds((const __attribute__((address_space(1))) u32*)g,
                                   (__attribute__((address_space(3))) u32*)l, 16, 0, 0);
}

// staging modes for gemm64 operands
#define MBF 0   // bf16 [row][k] via global_load_lds (pre-swizzled source chunk)
#define MF32 1  // fp32 [row][k]: reg-load float4x2 -> cvt_pk -> swizzled ds_write
#define MTR 2   // fp32 W[k][n] (transposed source): lane=n coalesced column staging

// ---------- 64x128 bf16 GEMM core, double-buffered single-barrier pipeline ----------
// acc = A[64-tile(m0),K] * B[128-tile(n0),K]^T, K=1024, BK=64, 16 iters.
// LDS per buffer: [rows][64] u16, 16B chunks XOR-swizzled: chunk c of row r at c^(r&7).
template <int AM, int BM>
__device__ __forceinline__ void gemm64(const void* __restrict__ A, const void* __restrict__ B,
                                       int m0, int n0, int ldA, int ldB, u16* lA, u16* lB,
                                       f32x4 acc[2][4]) {
  const int tid = threadIdx.x;
  const int lane = tid & 63, wave = tid >> 6;
  const int l15 = lane & 15, quad = lane >> 4;
  const int wm = wave >> 1, wn = wave & 1;
  const int sr = tid >> 3, sch = tid & 7;                    // MF32: row, chunk
  const int gr = lane >> 3, gch = (lane & 7) ^ (lane >> 3);  // MBF: row-in-slab, src chunk
  const int nb = tid & 127, ko = tid >> 7;                   // MTR-B: col, k-half
  f32x4 zero = {0.f, 0.f, 0.f, 0.f};
#pragma unroll
  for (int i = 0; i < 2; i++)
#pragma unroll
    for (int j = 0; j < 4; j++) acc[i][j] = zero;

  float rA[16], rB[32];  // reg staging (unused modes DCE'd); all indices static

  auto issue = [&](int k0, u16* dA, u16* dB) {
    if constexpr (AM == MBF) {
#pragma unroll
      for (int it = 0; it < 2; it++) {
        int w8 = wave * 2 + it;
        gload16((const u16*)A + (size_t)(m0 + w8 * 8 + gr) * ldA + k0 + gch * 8,
                dA + w8 * 512);
      }
    } else if constexpr (AM == MF32) {
#pragma unroll
      for (int it = 0; it < 2; it++) {
        const float* p = (const float*)A + (size_t)(m0 + sr + it * 32) * ldA + k0 + sch * 8;
        float4 a = *(const float4*)p, b = *(const float4*)(p + 4);
        rA[it * 8 + 0] = a.x; rA[it * 8 + 1] = a.y; rA[it * 8 + 2] = a.z; rA[it * 8 + 3] = a.w;
        rA[it * 8 + 4] = b.x; rA[it * 8 + 5] = b.y; rA[it * 8 + 6] = b.z; rA[it * 8 + 7] = b.w;
      }
    } else {  // MTR-A: rows = W columns m0+lane; wave covers k-octets 2w,2w+1
      const float* Wf = (const float*)A;
#pragma unroll
      for (int j = 0; j < 16; j++)
        rA[j] = Wf[(size_t)(k0 + wave * 16 + j) * ldA + m0 + lane];
    }
    if constexpr (BM == MBF) {
#pragma unroll
      for (int it = 0; it < 4; it++) {
        int w8 = wave * 4 + it;
        gload16((const u16*)B + (size_t)(n0 + w8 * 8 + gr) * ldB + k0 + gch * 8,
                dB + w8 * 512);
      }
    } else if constexpr (BM == MF32) {
#pragma unroll
      for (int it = 0; it < 4; it++) {
        const float* p = (const float*)B + (size_t)(n0 + sr + it * 32) * ldB + k0 + sch * 8;
        float4 a = *(const float4*)p, b = *(const float4*)(p + 4);
        rB[it * 8 + 0] = a.x; rB[it * 8 + 1] = a.y; rB[it * 8 + 2] = a.z; rB[it * 8 + 3] = a.w;
        rB[it * 8 + 4] = b.x; rB[it * 8 + 5] = b.y; rB[it * 8 + 6] = b.z; rB[it * 8 + 7] = b.w;
      }
    } else {  // MTR-B: rows = W columns n0+nb; thread covers k-half ko (32 k's)
      const float* Wf = (const float*)B;
#pragma unroll
      for (int j = 0; j < 32; j++)
        rB[j] = Wf[(size_t)(k0 + ko * 32 + j) * ldB + n0 + nb];
    }
  };

  auto wrb = [&](u16* dA, u16* dB) {
    if constexpr (AM == MF32) {
#pragma unroll
      for (int it = 0; it < 2; it++) {
        int r = sr + it * 32;
        uint4 v;
        v.x = pack2(rA[it * 8 + 0], rA[it * 8 + 1]);
        v.y = pack2(rA[it * 8 + 2], rA[it * 8 + 3]);
        v.z = pack2(rA[it * 8 + 4], rA[it * 8 + 5]);
        v.w = pack2(rA[it * 8 + 6], rA[it * 8 + 7]);
        *(uint4*)&dA[r * 64 + ((sch ^ (r & 7)) << 3)] = v;
      }
    } else if constexpr (AM == MTR) {
#pragma unroll
      for (int o = 0; o < 2; o++) {
        uint4 v;
        v.x = pack2(rA[o * 8 + 0], rA[o * 8 + 1]);
        v.y = pack2(rA[o * 8 + 2], rA[o * 8 + 3]);
        v.z = pack2(rA[o * 8 + 4], rA[o * 8 + 5]);
        v.w = pack2(rA[o * 8 + 6], rA[o * 8 + 7]);
        int c = (wave * 2 + o) ^ (lane & 7);
        *(uint4*)&dA[lane * 64 + (c << 3)] = v;  // 2 lanes/bank -> conflict-free
      }
    }
    if constexpr (BM == MF32) {
#pragma unroll
      for (int it = 0; it < 4; it++) {
        int r = sr + it * 32;
        uint4 v;
        v.x = pack2(rB[it * 8 + 0], rB[it * 8 + 1]);
        v.y = pack2(rB[it * 8 + 2], rB[it * 8 + 3]);
        v.z = pack2(rB[it * 8 + 4], rB[it * 8 + 5]);
        v.w = pack2(rB[it * 8 + 6], rB[it * 8 + 7]);
        *(uint4*)&dB[r * 64 + ((sch ^ (r & 7)) << 3)] = v;
      }
    } else if constexpr (BM == MTR) {
#pragma unroll
      for (int o = 0; o < 4; o++) {
        uint4 v;
        v.x = pack2(rB[o * 8 + 0], rB[o * 8 + 1]);
        v.y = pack2(rB[o * 8 + 2], rB[o * 8 + 3]);
        v.z = pack2(rB[o * 8 + 4], rB[o * 8 + 5]);
        v.w = pack2(rB[o * 8 + 6], rB[o * 8 + 7]);
        int c = (ko * 4 + o) ^ (nb & 7);
        *(uint4*)&dB[nb * 64 + (c << 3)] = v;
      }
    }
  };

  issue(0, lA, lB);
  wrb(lA, lB);
  __syncthreads();

  for (int t = 0; t < 16; t++) {
    u16* cA = lA + (t & 1) * 4096;
    u16* cB = lB + (t & 1) * 8192;
    u16* nA = lA + ((t + 1) & 1) * 4096;
    u16* nB = lB + ((t + 1) & 1) * 8192;
    if (t < 15) issue((t + 1) * 64, nA, nB);
    short8 af[2][2], bfr[4][2];
#pragma unroll
    for (int i = 0; i < 2; i++)
#pragma unroll
      for (int kb = 0; kb < 2; kb++) {
        int r = wm * 32 + i * 16 + l15;
        af[i][kb] = *(const short8*)&cA[r * 64 + (((kb * 4 + quad) ^ (r & 7)) << 3)];
      }
#pragma unroll
    for (int j = 0; j < 4; j++)
#pragma unroll
      for (int kb = 0; kb < 2; kb++) {
        int r = wn * 64 + j * 16 + l15;
        bfr[j][kb] = *(const short8*)&cB[r * 64 + (((kb * 4 + quad) ^ (r & 7)) << 3)];
      }
#pragma unroll
    for (int i = 0; i < 2; i++)
#pragma unroll
      for (int j = 0; j < 4; j++) {
        acc[i][j] = MFMA16(af[i][0], bfr[j][0], acc[i][j]);
        acc[i][j] = MFMA16(af[i][1], bfr[j][1], acc[i][j]);
      }
    if (t < 15) wrb(nA, nB);
    __syncthreads();
  }
}

// ---------- k_pre: K/V projection (MTR weights, no prep dependency) + Wq/Wo transpose
// + query->bf16, all in ONE launch.  GEMM blocks first (tail-minimizing):
//   [0,128)      K-proj: A=Wk fp32 MTR (ld 256), B=key_in MF32; m0=(i>>5)*64, n0=(i&31)*128
//   [128,256)    V-proj: A=value_in MF32, B=Wv fp32 MTR; m0=(vi>>1)*64, n0=(vi&1)*128
//   [256,1280)   Wq transpose -> WqT bf16
//   [1280,2304)  Wo transpose -> WoT bf16
//   [2304,3328)  query -> qact bf16 (RNE)
__global__ __launch_bounds__(256, 3) void k_pre(
    const float* __restrict__ Wq, const float* __restrict__ Wk, const float* __restrict__ Wv,
    const float* __restrict__ Wo, const float* __restrict__ query,
    const float* __restrict__ key_in, const float* __restrict__ value_in,
    const float* __restrict__ bk, const float* __restrict__ bv, u16* __restrict__ WqT,
    u16* __restrict__ WoT, u16* __restrict__ qact, float* __restrict__ outK,
    u16* __restrict__ kbf, float* __restrict__ outV, u16* __restrict__ vtb) {
  __shared__ u16 lsd[2 * 4096 + 2 * 8192];  // GEMM: lA|lB ; transpose: aliased tile
  const int idx = blockIdx.x;
  const int tid = threadIdx.x;

  if (idx < 256) {
    u16* lA = lsd;
    u16* lB = lsd + 2 * 4096;
    const int lane = tid & 63, wave = tid >> 6;
    const int l15 = lane & 15, quad = lane >> 4;
    const int wm = wave >> 1, wn = wave & 1;
    f32x4 acc[2][4];
    if (idx < 128) {
      int m0 = (idx >> 5) * 64, n0 = (idx & 31) * 128;
      gemm64<MTR, MF32>(Wk, key_in, m0, n0, 256, 1024, lA, lB, acc);
#pragma unroll
      for (int i = 0; i < 2; i++) {
        int c0 = m0 + wm * 32 + i * 16 + quad * 4;
        float4 bb = *(const float4*)(bk + c0);
#pragma unroll
        for (int j = 0; j < 4; j++) {
          int token = n0 + wn * 64 + j * 16 + l15;
          int b = token >> 11, s = token & 2047;
          float v0 = acc[i][j][0] + bb.x, v1 = acc[i][j][1] + bb.y;
          float v2 = acc[i][j][2] + bb.z, v3 = acc[i][j][3] + bb.w;
          int d = c0 & 63, kvh = c0 >> 6;
          size_t ix = (((size_t)(b * 4 + kvh) * SEQ + s) << 6) + d;
          float4 vv = {v0, v1, v2, v3};
          *(float4*)(outK + ix) = vv;
          uint2 ob;
          ob.x = pack2(v0, v1);
          ob.y = pack2(v2, v3);
          *(uint2*)(kbf + ix) = ob;
        }
      }
    } else {
      int vi = idx - 128;
      int m0 = (vi >> 1) * 64, n0 = (vi & 1) * 128;
      gemm64<MF32, MTR>(value_in, Wv, m0, n0, 1024, 256, lA, lB, acc);
#pragma unroll
      for (int i = 0; i < 2; i++) {
        int r0 = m0 + wm * 32 + i * 16 + quad * 4;  // token, 4-aligned
        int b = r0 >> 11, s0 = r0 & 2047;
#pragma unroll
        for (int j = 0; j < 4; j++) {
          int col = n0 + wn * 64 + j * 16 + l15;
          int kvh = col >> 6, d = col & 63;
          float bv_ = bv[col];
          float v0 = acc[i][j][0] + bv_, v1 = acc[i][j][1] + bv_;
          float v2 = acc[i][j][2] + bv_, v3 = acc[i][j][3] + bv_;
          size_t base = (((size_t)(b * 4 + kvh) * SEQ + s0) << 6) + d;
          outV[base] = v0;
          outV[base + 64] = v1;
          outV[base + 128] = v2;
          outV[base + 192] = v3;
          uint2 ob;
          ob.x = pack2(v0, v1);
          ob.y = pack2(v2, v3);
          *(uint2*)(vtb + ((size_t)(b * 4 + kvh) * 64 + d) * SEQ + s0) = ob;  // V^T
        }
      }
    }
  } else if (idx < 2304) {
    // weight transpose: W[1024,1024] fp32 -> Wt[1024,1024] bf16
    float(*tile)[33] = (float(*)[33])lsd;
    int wi = idx - 256;
    const float* W = wi < 1024 ? Wq : Wo;
    u16* Wt = wi < 1024 ? WqT : WoT;
    wi &= 1023;
    const int n0 = (wi & 31) * 32, k0 = (wi >> 5) * 32;
    int x = tid & 31, y = tid >> 5;
#pragma unroll
    for (int i = 0; i < 4; i++)
      tile[y + i * 8][x] = W[(size_t)(k0 + y + i * 8) * 1024 + n0 + x];
    __syncthreads();
#pragma unroll
    for (int i = 0; i < 4; i++)
      Wt[(size_t)(n0 + y + i * 8) * 1024 + k0 + x] = f2bf(tile[x][y + i * 8]);
  } else {
    // query conversion: 1024 blocks x 4096 elems (16 floats/thread)
    size_t base = (size_t)(idx - 2304) * 4096 + tid * 16;
    const float* p = query + base;
    uint4 o0, o1;
    float4 a = *(const float4*)p, b = *(const float4*)(p + 4);
    float4 c = *(const float4*)(p + 8), d = *(const float4*)(p + 12);
    o0.x = pack2(a.x, a.y); o0.y = pack2(a.z, a.w);
    o0.z = pack2(b.x, b.y); o0.w = pack2(b.z, b.w);
    o1.x = pack2(c.x, c.y); o1.y = pack2(c.z, c.w);
    o1.z = pack2(d.x, d.y); o1.w = pack2(d.z, d.w);
    *(uint4*)(qact + base) = o0;
    *(uint4*)(qact + base + 8) = o1;
  }
}

// ---------- flash attention with FUSED Q-projection ----------
// grid (S/128, B*H).  Prologue: Q-tile = qact[tokens] . WqT[h*64..h*64+64] via
// gemm64<MBF,MBF> using flash's LDS (lA=lK[0], lB=lV, both exact-size), epilogue
// (acc+bq)*qscale RNE-packed -> swizzled lQ=lK[1]; qf fragments read back (identical
// values to the old qbf path).  Then the R4 flash body: register-resident P,
// double-buffered K/V staging (stage t=1 overwrites lK[1] only after qf is in regs).
__global__ __launch_bounds__(256, 2) void k_flash(const u16* __restrict__ qact,
                                                  const u16* __restrict__ WqT,
                                                  const float* __restrict__ bq,
                                                  const u16* __restrict__ Kb,
                                                  const u16* __restrict__ Vt,
                                                  u16* __restrict__ ctx, float qscale) {
  __shared__ u16 lK[2][128 * 64];  // [key][d], 8 chunks/row, chunk' = ch ^ (row&7)
  __shared__ u16 lV[2][64 * 128];  // [d][key], 16 chunks/row, chunk' = ch ^ (row&15)
  const int tid = threadIdx.x;
  const int lane = tid & 63, wave = tid >> 6;
  const int l15 = lane & 15, quad = lane >> 4;
  const int bh = blockIdx.y;
  const int b = bh >> 4, h = bh & 15, kvh = h >> 2;
  const u16* Kp = Kb + (size_t)(b * 4 + kvh) * SEQ * 64;
  const u16* Vp = Vt + (size_t)(b * 4 + kvh) * 64 * SEQ;
  const int wm = wave >> 1, wn = wave & 1;

  // ---- fused Q projection: 64 cols (head h) x 128 tokens ----
  u16* lA = (u16*)lK;             // 8192 u16 = 2 x 4096 (exact)
  u16* lB = (u16*)lV;             // 16384 u16 = 2 x 8192 (exact)
  u16* lQ = (u16*)lK + 8192;      // lK[1] region: 128 x 64 u16 (exact)
  {
    f32x4 qa[2][4];
    gemm64<MBF, MBF>(WqT, qact, h * 64, b * SEQ + blockIdx.x * 128, 1024, 1024, lA, lB, qa);
#pragma unroll
    for (int i = 0; i < 2; i++) {
      int c0 = wm * 32 + i * 16 + quad * 4;  // local d, 4-aligned
      float4 bb = *(const float4*)(bq + h * 64 + c0);
#pragma unroll
      for (int j = 0; j < 4; j++) {
        int row = wn * 64 + j * 16 + l15;  // local token 0..127
        uint2 o;
        o.x = pack2((qa[i][j][0] + bb.x) * qscale, (qa[i][j][1] + bb.y) * qscale);
        o.y = pack2((qa[i][j][2] + bb.z) * qscale, (qa[i][j][3] + bb.w) * qscale);
        int chq = c0 >> 3;  // = wm*4 + i*2 + (quad>>1)
        *(uint2*)&lQ[row * 64 + ((chq ^ (row & 7)) << 3) + (quad & 1) * 4] = o;
      }
    }
  }
  __syncthreads();  // lQ complete (cross-wave)

  // Q B-operand fragments for both 16-q groups (n=q, k=quad*8+j), resident all pass
  short8 qf[2][2];
#pragma unroll
  for (int g = 0; g < 2; g++)
#pragma unroll
    for (int kb = 0; kb < 2; kb++) {
      int row = wave * 32 + g * 16 + l15;
      qf[g][kb] = *(const short8*)&lQ[row * 64 + (((kb * 4 + quad) ^ (row & 7)) << 3)];
    }

  short8 ones8;
  {
    short ov = (l15 == 0) ? (short)0x3F80 : (short)0;
    ones8 = (short8){ov, ov, ov, ov, ov, ov, ov, ov};
  }

  f32x4 zero = {0.f, 0.f, 0.f, 0.f};
  f32x4 acc[2][4];  // O^T per group: acc[g][n] rows d=n*16+quad*4+r, col q=l15
  f32x4 lacc[2] = {zero, zero};
#pragma unroll
  for (int g = 0; g < 2; g++)
#pragma unroll
    for (int n = 0; n < 4; n++) acc[g][n] = zero;

  const int gr3 = lane >> 3, gc7 = lane & 7;    // K staging: row-in-slab, chunk
  const int gr4 = lane >> 4, gc15 = lane & 15;  // V staging
  const int q0 = blockIdx.x * 128 + wave * 32;

  auto stage = [&](int kc, int bufi) {
    u16* dK = lK[bufi];
    u16* dV = lV[bufi];
#pragma unroll
    for (int i = 0; i < 4; i++) {
      int slab = wave * 4 + i;
      gload16(Kp + (size_t)(kc + slab * 8 + gr3) * 64 + ((gc7 ^ gr3) << 3), dK + slab * 512);
    }
#pragma unroll
    for (int i = 0; i < 4; i++) {
      int slab = wave * 4 + i;
      int row = slab * 4 + gr4;
      gload16(Vp + (size_t)row * SEQ + kc + ((gc15 ^ (row & 15)) << 3), dV + slab * 512);
    }
  };

  __syncthreads();  // all waves have qf in registers; LDS free for staging
  stage(0, 0);
  __syncthreads();

  for (int t = 0; t < SEQ / 128; t++) {
    if (t < SEQ / 128 - 1) stage((t + 1) * 128, (t + 1) & 1);  // async prefetch
    const u16* cK = lK[t & 1];
    const u16* cV = lV[t & 1];

#pragma unroll
    for (int sub = 0; sub < 2; sub++) {
      const int ks = sub * 64;
      f32x4 sc[2][4];
#pragma unroll
      for (int mt = 0; mt < 4; mt++) {
        int row = ks + mt * 16 + l15;
        short8 kf0 = *(const short8*)&cK[row * 64 + ((quad ^ (row & 7)) << 3)];
        short8 kf1 = *(const short8*)&cK[row * 64 + (((4 + quad) ^ (row & 7)) << 3)];
#pragma unroll
        for (int g = 0; g < 2; g++) {
          f32x4 t0 = MFMA16(kf0, qf[g][0], zero);
          sc[g][mt] = MFMA16(kf1, qf[g][1], t0);
        }
      }
#pragma unroll
      for (int g = 0; g < 2; g++)
#pragma unroll
        for (int mt = 0; mt < 4; mt++)
#pragma unroll
          for (int r = 0; r < 4; r++) sc[g][mt][r] = __builtin_amdgcn_exp2f(sc[g][mt][r]);

#pragma unroll
      for (int kbp = 0; kbp < 2; kbp++) {
        short8 pf[2];
#pragma unroll
        for (int g = 0; g < 2; g++) {
          u32 U0 = pack2t(sc[g][2 * kbp][0], sc[g][2 * kbp][1]);
          u32 W0 = pack2t(sc[g][2 * kbp + 1][0], sc[g][2 * kbp + 1][1]);
          u32 U1 = pack2t(sc[g][2 * kbp][2], sc[g][2 * kbp][3]);
          u32 W1 = pack2t(sc[g][2 * kbp + 1][2], sc[g][2 * kbp + 1][3]);
          pswap32(U0, W0);
          pswap16(U0, W0);
          pswap32(U1, W1);
          pswap16(U1, W1);
          u32 w[4] = {U0, U1, W0, W1};  // F0..F3
          pf[g] = *(const short8*)w;
        }
        lacc[0] = MFMA16(ones8, pf[0], lacc[0]);
        lacc[1] = MFMA16(ones8, pf[1], lacc[1]);
#pragma unroll
        for (int n = 0; n < 4; n++) {
          int row = n * 16 + l15;
          int chv = sub * 8 + kbp * 4 + quad;
          short8 vf = *(const short8*)&cV[row * 128 + ((chv ^ (row & 15)) << 3)];
          acc[0][n] = MFMA16(vf, pf[0], acc[0][n]);
          acc[1][n] = MFMA16(vf, pf[1], acc[1][n]);
        }
      }
    }
    __syncthreads();
  }

#pragma unroll
  for (int g = 0; g < 2; g++) {
    float lq = __shfl(lacc[g][0], l15);
    float inv = __builtin_amdgcn_rcpf(lq);
    u16* base = ctx + ((size_t)(b * SEQ + q0 + g * 16 + l15)) * DM + h * 64;
#pragma unroll
    for (int n = 0; n < 4; n++) {
      uint2 o;
      o.x = pack2t(acc[g][n][0] * inv, acc[g][n][1] * inv);
      o.y = pack2t(acc[g][n][2] * inv, acc[g][n][3] * inv);
      *(uint2*)(base + n * 16 + quad * 4) = o;
    }
  }
}

// ---------- output projection: A=WoT (MBF), B=ctxb (MBF), 512 blocks ----------
__global__ __launch_bounds__(256, 3) void k_out(const u16* __restrict__ ctxb,
                                                const u16* __restrict__ WoT,
                                                const float* __restrict__ bo,
                                                float* __restrict__ out) {
  __shared__ u16 lA[2 * 4096];
  __shared__ u16 lB[2 * 8192];
  const int idx = blockIdx.x;
  const int m0 = (idx >> 5) * 64, n0 = (idx & 31) * 128;
  const int lane = threadIdx.x & 63, wave = threadIdx.x >> 6;
  const int l15 = lane & 15, quad = lane >> 4;
  const int wm = wave >> 1, wn = wave & 1;
  f32x4 acc[2][4];
  gemm64<MBF, MBF>(WoT, ctxb, m0, n0, 1024, 1024, lA, lB, acc);
#pragma unroll
  for (int i = 0; i < 2; i++) {
    int c0 = m0 + wm * 32 + i * 16 + quad * 4;
    float4 bb = *(const float4*)(bo + c0);
#pragma unroll
    for (int j = 0; j < 4; j++) {
      int token = n0 + wn * 64 + j * 16 + l15;
      float4 vv = {acc[i][j][0] + bb.x, acc[i][j][1] + bb.y, acc[i][j][2] + bb.z,
                   acc[i][j][3] + bb.w};
      *(float4*)(out + (size_t)token * DM + c0) = vv;
    }
  }
}

extern "C" void kernel_launch(void* const* d_in, const int* in_sizes, int n_in,
                              void* d_out, int out_size, void* d_ws, size_t ws_size,
                              hipStream_t stream) {
  const float* query = (const float*)d_in[0];
  const float* key_in = (const float*)d_in[1];
  const float* value_in = (const float*)d_in[2];
  const float* Wq = (const float*)d_in[3];
  const float* bq = (const float*)d_in[4];
  const float* Wk = (const float*)d_in[5];
  const float* bk = (const float*)d_in[6];
  const float* Wv = (const float*)d_in[7];
  const float* bv = (const float*)d_in[8];
  const float* Wo = (const float*)d_in[9];
  const float* bo = (const float*)d_in[10];

  float* out = (float*)d_out;   // [B,S,DM]
  float* outK = out + 4194304;  // [B,KVH,S,64]
  float* outV = out + 5242880;  // [B,KVH,S,64]

  char* ws = (char*)d_ws;
  u16* WqT = (u16*)(ws);               // 2M  [1024 outcols][1024 k] bf16
  u16* WoT = (u16*)(ws + 2097152);     // 2M
  u16* qact = (u16*)(ws + 4194304);    // 8M  query bf16 [B*S,1024]
  u16* ctxb = (u16*)(ws + 12582912);   // 8M  ctx bf16 [B,S,DM]  (NOT aliased: flash reads qact)
  u16* kbf = (u16*)(ws + 20971520);    // 2M  K bf16 [B,KVH,S,64]
  u16* vtb = (u16*)(ws + 23068672);    // 2M  V^T bf16 [B,KVH,64,S]
  // high-water: 25,165,824 bytes (<= prior 26,214,400)

  const float qscale = 0.125f * 1.44269504088896340736f;  // fold log2(e) -> exp2 softmax

  k_pre<<<dim3(3328), 256, 0, stream>>>(Wq, Wk, Wv, Wo, query, key_in, value_in, bk, bv,
                                        WqT, WoT, qact, outK, kbf, outV, vtb);
  k_flash<<<dim3(16, 32), 256, 0, stream>>>(qact, WqT, bq, kbf, vtb, ctxb, qscale);
  k_out<<<dim3(512), 256, 0, stream>>>(ctxb, WoT, bo, out);
}

// Round 11
// 200.524 us; speedup vs baseline: 1.1228x; 1.0377x over previous
//
#include <hip/hip_runtime.h>

typedef unsigned short u16;
typedef unsigned int u32;
typedef __attribute__((ext_vector_type(8))) short short8;
typedef __attribute__((ext_vector_type(4))) float f32x4;

#define MFMA16(a, b, c) __builtin_amdgcn_mfma_f32_16x16x32_bf16(a, b, c, 0, 0, 0)

// B=2, S=2048, D=1024, H=16, KVH=4, dk=64, G=4
#define SEQ 2048
#define DM 1024

__device__ __forceinline__ u16 f2bf(float f) {
  u32 u = __float_as_uint(f);
  u += 0x7fffu + ((u >> 16) & 1u);  // RNE
  return (u16)(u >> 16);
}
// RNE pack via HW packed convert (gfx950): 1 instruction, same rounding as f2bf
__device__ __forceinline__ u32 pack2(float a, float b) {
  u32 r;
  asm("v_cvt_pk_bf16_f32 %0, %1, %2" : "=v"(r) : "v"(a), "v"(b));
  return r;
}
__device__ __forceinline__ u32 pack2t(float a, float b) {  // truncating pack: 1 v_perm
  return __builtin_amdgcn_perm(__float_as_uint(b), __float_as_uint(a), 0x07060302u);
}
// two-register cross-lane swaps (gfx950): modify both operands in place
__device__ __forceinline__ void pswap32(u32& a, u32& b) {
  asm("v_permlane32_swap_b32 %0, %1" : "+v"(a), "+v"(b));
}
__device__ __forceinline__ void pswap16(u32& a, u32& b) {
  asm("v_permlane16_swap_b32 %0, %1" : "+v"(a), "+v"(b));
}
// 8 fp32 -> bf16x8 (uint4) with RNE, 4 cvt_pk instructions
__device__ __forceinline__ uint4 cvt8(const float* f) {
  float4 a = *(const float4*)f;
  float4 b = *(const float4*)(f + 4);
  uint4 r;
  r.x = pack2(a.x, a.y);
  r.y = pack2(a.z, a.w);
  r.z = pack2(b.x, b.y);
  r.w = pack2(b.z, b.w);
  return r;
}
// async global->LDS, 16B per lane; dest = wave-uniform base + lane*16
__device__ __forceinline__ void gload16(const u16* g, u16* l) {
  __builtin_amdgcn_global_load_lds((const __attribute__((address_space(1))) u32*)g,
                                   (__attribute__((address_space(3))) u32*)l, 16, 0, 0);
}

// ---------- weight transposes W[K,N] fp32 -> Wt[N,K] bf16 ----------
__global__ void k_tr(const float* __restrict__ Wq, const float* __restrict__ Wk,
                     const float* __restrict__ Wv, const float* __restrict__ Wo,
                     u16* __restrict__ WqT, u16* __restrict__ WkT, u16* __restrict__ WvT,
                     u16* __restrict__ WoT) {
  const int z = blockIdx.z;
  const float* W = z == 0 ? Wq : (z == 1 ? Wk : (z == 2 ? Wv : Wo));
  u16* Wt = z == 0 ? WqT : (z == 1 ? WkT : (z == 2 ? WvT : WoT));
  const int N = (z == 1 || z == 2) ? 256 : 1024;
  const int n0 = blockIdx.x * 32;
  if (n0 >= N) return;
  const int k0 = blockIdx.y * 32;
  __shared__ float tile[32][33];
  int x = threadIdx.x & 31, y = threadIdx.x >> 5;
#pragma unroll
  for (int i = 0; i < 4; i++)
    tile[y + i * 8][x] = W[(size_t)(k0 + y + i * 8) * N + n0 + x];
  __syncthreads();
#pragma unroll
  for (int i = 0; i < 4; i++)
    Wt[(size_t)(n0 + y + i * 8) * 1024 + k0 + x] = f2bf(tile[x][y + i * 8]);
}

// ---------- 64x128 bf16 GEMM core: acc = A[64-tile,K] * Bt[128-tile,K]^T, K=1024 ----------
// LDS layout: linear [row][64] u16 (128B rows), 16B chunks XOR-swizzled: LDS chunk c of
// row r holds global chunk c ^ (r&7).  bf16 operands stage via global_load_lds (linear
// dest + pre-swizzled SOURCE chunk); fp32 operands reg-stage with v_cvt_pk_bf16_f32 and
// write the swizzled chunk directly.  Fragment reads apply the same XOR -> conflict-free.
// waves: wm=wave>>1 picks 32-row half (2 mtiles), wn=wave&1 picks 64-col half (4 ntiles)
template <bool A32, bool B32>
__device__ __forceinline__ void gemm64(const void* __restrict__ A, const void* __restrict__ Bt,
                                       int m0, int n0, u16* lA, u16* lB, f32x4 acc[2][4]) {
  const int tid = threadIdx.x;
  const int lane = tid & 63, wave = tid >> 6;
  const int l15 = lane & 15, quad = lane >> 4;
  const int wm = wave >> 1, wn = wave & 1;
  const int sr = tid >> 3, scol = (tid & 7) * 8;
  f32x4 zero = {0.f, 0.f, 0.f, 0.f};
#pragma unroll
  for (int i = 0; i < 2; i++)
#pragma unroll
    for (int j = 0; j < 4; j++) acc[i][j] = zero;

  for (int k0 = 0; k0 < 1024; k0 += 64) {
    // ---- stage A tile (64 rows) ----
    if constexpr (A32) {
      const float* Af = (const float*)A;
#pragma unroll
      for (int it = 0; it < 2; it++) {
        int r = sr + it * 32;
        uint4 v = cvt8(Af + (size_t)(m0 + r) * 1024 + k0 + scol);
        *(uint4*)&lA[r * 64 + (((tid & 7) ^ (r & 7)) << 3)] = v;
      }
    } else {
      const u16* Ab = (const u16*)A;
#pragma unroll
      for (int it = 0; it < 2; it++) {
        int w8 = wave * 2 + it;               // 8-row slab index 0..7
        int r = w8 * 8 + (lane >> 3);         // r&7 == lane>>3
        int g = (lane & 7) ^ (lane >> 3);     // source chunk so data lands swizzled
        gload16(Ab + (size_t)(m0 + r) * 1024 + k0 + g * 8, &lA[w8 * 512]);
      }
    }
    // ---- stage B tile (128 rows) ----
    if constexpr (B32) {
      const float* Bf = (const float*)Bt;
#pragma unroll
      for (int it = 0; it < 4; it++) {
        int r = sr + it * 32;
        uint4 v = cvt8(Bf + (size_t)(n0 + r) * 1024 + k0 + scol);
        *(uint4*)&lB[r * 64 + (((tid & 7) ^ (r & 7)) << 3)] = v;
      }
    } else {
      const u16* Bb = (const u16*)Bt;
#pragma unroll
      for (int it = 0; it < 4; it++) {
        int w8 = wave * 4 + it;               // 8-row slab index 0..15
        int r = w8 * 8 + (lane >> 3);
        int g = (lane & 7) ^ (lane >> 3);
        gload16(Bb + (size_t)(n0 + r) * 1024 + k0 + g * 8, &lB[w8 * 512]);
      }
    }
    __syncthreads();  // drains vmcnt (gload_lds) + lgkm (ds_write)
    short8 af[2][2], bfr[4][2];
#pragma unroll
    for (int i = 0; i < 2; i++)
#pragma unroll
      for (int kb = 0; kb < 2; kb++) {
        int r = wm * 32 + i * 16 + l15;
        af[i][kb] = *(const short8*)&lA[r * 64 + (((kb * 4 + quad) ^ (r & 7)) << 3)];
      }
#pragma unroll
    for (int j = 0; j < 4; j++)
#pragma unroll
      for (int kb = 0; kb < 2; kb++) {
        int r = wn * 64 + j * 16 + l15;
        bfr[j][kb] = *(const short8*)&lB[r * 64 + (((kb * 4 + quad) ^ (r & 7)) << 3)];
      }
#pragma unroll
    for (int i = 0; i < 2; i++)
#pragma unroll
      for (int j = 0; j < 4; j++) {
        acc[i][j] = MFMA16(af[i][0], bfr[j][0], acc[i][j]);
        acc[i][j] = MFMA16(af[i][1], bfr[j][1], acc[i][j]);
      }
    __syncthreads();
  }
}

// ---------- fused Q/K/V projection ----------
// flat grid 768: [0,512) Q (A=WqT gload, B=query fp32 cvt-stage)
//                [512,640) K (A=WkT gload, B=key_in fp32 cvt-stage)
//                [640,768) V (A=value_in fp32 cvt-stage, B=WvT gload)
__global__ __launch_bounds__(256) void k_proj(
    const float* __restrict__ query, const float* __restrict__ key_in,
    const float* __restrict__ value_in, const u16* __restrict__ WqT,
    const u16* __restrict__ WkT, const u16* __restrict__ WvT, const float* __restrict__ bq,
    const float* __restrict__ bk, const float* __restrict__ bv, u16* __restrict__ qbf,
    float* __restrict__ outK, u16* __restrict__ kbf, float* __restrict__ outV,
    u16* __restrict__ vtb, float qscale) {
  __shared__ u16 lA[64 * 64];
  __shared__ u16 lB[128 * 64];
  const int idx = blockIdx.x;
  const int lane = threadIdx.x & 63, wave = threadIdx.x >> 6;
  const int l15 = lane & 15, quad = lane >> 4;
  const int wm = wave >> 1, wn = wave & 1;
  f32x4 acc[2][4];

  if (idx < 640) {
    const u16* Wt;
    const float* act;
    const float* bias;
    int m0, n0, mode;
    if (idx < 512) {
      Wt = WqT; act = query; bias = bq; m0 = (idx >> 5) * 64; n0 = (idx & 31) * 128; mode = 0;
    } else {
      int i2 = idx - 512;
      Wt = WkT; act = key_in; bias = bk; m0 = (i2 >> 5) * 64; n0 = (i2 & 31) * 128; mode = 1;
    }
    gemm64<false, true>(Wt, act, m0, n0, lA, lB, acc);
#pragma unroll
    for (int i = 0; i < 2; i++) {
      int c0 = m0 + wm * 32 + i * 16 + quad * 4;  // output col, 4-aligned
      float4 bb = *(const float4*)(bias + c0);
#pragma unroll
      for (int j = 0; j < 4; j++) {
        int token = n0 + wn * 64 + j * 16 + l15;
        int b = token >> 11, s = token & 2047;
        float v0 = acc[i][j][0] + bb.x, v1 = acc[i][j][1] + bb.y;
        float v2 = acc[i][j][2] + bb.z, v3 = acc[i][j][3] + bb.w;
        int d = c0 & 63;
        if (mode == 0) {
          int h = c0 >> 6;
          uint2 o;
          o.x = pack2(v0 * qscale, v1 * qscale);
          o.y = pack2(v2 * qscale, v3 * qscale);
          *(uint2*)(qbf + (((size_t)(b * 16 + h) * SEQ + s) << 6) + d) = o;
        } else {
          int kvh = c0 >> 6;
          size_t ix = (((size_t)(b * 4 + kvh) * SEQ + s) << 6) + d;
          float4 vv = {v0, v1, v2, v3};
          *(float4*)(outK + ix) = vv;
          uint2 o;
          o.x = pack2(v0, v1);
          o.y = pack2(v2, v3);
          *(uint2*)(kbf + ix) = o;
        }
      }
    }
  } else {
    int i2 = idx - 640;
    int m0 = (i2 >> 1) * 64, n0 = (i2 & 1) * 128;
    gemm64<true, false>(value_in, WvT, m0, n0, lA, lB, acc);
#pragma unroll
    for (int i = 0; i < 2; i++) {
      int r0 = m0 + wm * 32 + i * 16 + quad * 4;  // token, 4-aligned
      int b = r0 >> 11, s0 = r0 & 2047;
#pragma unroll
      for (int j = 0; j < 4; j++) {
        int col = n0 + wn * 64 + j * 16 + l15;
        int kvh = col >> 6, d = col & 63;
        float bv_ = bv[col];
        float v0 = acc[i][j][0] + bv_, v1 = acc[i][j][1] + bv_;
        float v2 = acc[i][j][2] + bv_, v3 = acc[i][j][3] + bv_;
        size_t base = (((size_t)(b * 4 + kvh) * SEQ + s0) << 6) + d;
        outV[base] = v0;
        outV[base + 64] = v1;
        outV[base + 128] = v2;
        outV[base + 192] = v3;
        uint2 o;
        o.x = pack2(v0, v1);
        o.y = pack2(v2, v3);
        *(uint2*)(vtb + ((size_t)(b * 4 + kvh) * 64 + d) * SEQ + s0) = o;  // V^T
      }
    }
  }
}

// ---------- output projection (A=WoT gload, B=ctxb gload, both bf16) ----------
__global__ __launch_bounds__(256) void k_out(const u16* __restrict__ ctxb,
                                             const u16* __restrict__ WoT,
                                             const float* __restrict__ bo,
                                             float* __restrict__ out) {
  __shared__ u16 lA[64 * 64];
  __shared__ u16 lB[128 * 64];
  const int idx = blockIdx.x;
  const int m0 = (idx >> 5) * 64, n0 = (idx & 31) * 128;
  const int lane = threadIdx.x & 63, wave = threadIdx.x >> 6;
  const int l15 = lane & 15, quad = lane >> 4;
  const int wm = wave >> 1, wn = wave & 1;
  f32x4 acc[2][4];
  gemm64<false, false>(WoT, ctxb, m0, n0, lA, lB, acc);
#pragma unroll
  for (int i = 0; i < 2; i++) {
    int c0 = m0 + wm * 32 + i * 16 + quad * 4;
    float4 bb = *(const float4*)(bo + c0);
#pragma unroll
    for (int j = 0; j < 4; j++) {
      int token = n0 + wn * 64 + j * 16 + l15;
      float4 vv = {acc[i][j][0] + bb.x, acc[i][j][1] + bb.y, acc[i][j][2] + bb.z,
                   acc[i][j][3] + bb.w};
      *(float4*)(out + (size_t)token * DM + c0) = vv;
    }
  }
}

// ---------- flash attention: register-resident P, double-buffered K/V staging ----------
// grid (S/128, B*H); 4 waves x 32 q (2 groups of 16). K/V fragments shared across groups.
// P routed from QK^T C-layout to PV B-layout entirely in registers:
//   source: sc[g][mt][r] = P[key=mt*16+quad*4+r][q=l15]
//   target: pf elem j     = P[key=kbp*32+quad*8+j][q=l15]
//   route:  per word-pair a: U=pack(sc[2kbp][2a..]), W=pack(sc[2kbp+1][2a..]);
//           permlane32_swap(U,W); permlane16_swap(U,W) -> U=F[a], W=F[2+a].
// One barrier per 128-key segment; next segment's global_load_lds issued before compute.
// S^T = K.Q^T; no-max softmax (scores provably small); l via ones-row MFMA.
__global__ __launch_bounds__(256, 2) void k_flash(const u16* __restrict__ Qh,
                                                  const u16* __restrict__ Kb,
                                                  const u16* __restrict__ Vt,
                                                  u16* __restrict__ ctx) {
  __shared__ u16 lK[2][128 * 64];  // [key][d], 8 chunks/row, chunk' = ch ^ (row&7)
  __shared__ u16 lV[2][64 * 128];  // [d][key], 16 chunks/row, chunk' = ch ^ (row&15)
  const int tid = threadIdx.x;
  const int lane = tid & 63, wave = tid >> 6;
  const int l15 = lane & 15, quad = lane >> 4;
  const int bh = blockIdx.y;
  const int b = bh >> 4, h = bh & 15, kvh = h >> 2;
  const u16* Q = Qh + (size_t)bh * SEQ * 64;
  const u16* Kp = Kb + (size_t)(b * 4 + kvh) * SEQ * 64;
  const u16* Vp = Vt + (size_t)(b * 4 + kvh) * 64 * SEQ;
  const int q0 = blockIdx.x * 128 + wave * 32;

  // Q B-operand fragments for both 16-q groups (n=q, k=quad*8+j), resident all pass
  short8 qf[2][2];
#pragma unroll
  for (int g = 0; g < 2; g++)
#pragma unroll
    for (int kb = 0; kb < 2; kb++)
      qf[g][kb] = *(const short8*)(Q + (size_t)(q0 + g * 16 + l15) * 64 + kb * 32 + quad * 8);

  short8 ones8;
  {
    short ov = (l15 == 0) ? (short)0x3F80 : (short)0;
    ones8 = (short8){ov, ov, ov, ov, ov, ov, ov, ov};
  }

  f32x4 zero = {0.f, 0.f, 0.f, 0.f};
  f32x4 acc[2][4];  // O^T per group: acc[g][n] rows d=n*16+quad*4+r, col q=l15
  f32x4 lacc[2] = {zero, zero};
#pragma unroll
  for (int g = 0; g < 2; g++)
#pragma unroll
    for (int n = 0; n < 4; n++) acc[g][n] = zero;

  const int gr3 = lane >> 3, gc7 = lane & 7;    // K staging: row-in-slab, chunk
  const int gr4 = lane >> 4, gc15 = lane & 15;  // V staging

  // stage one 128-key segment (16KB K + 16KB V) into buffer bufi
  auto stage = [&](int kc, int bufi) {
    u16* dK = lK[bufi];
    u16* dV = lV[bufi];
#pragma unroll
    for (int i = 0; i < 4; i++) {
      int slab = wave * 4 + i;
      gload16(Kp + (size_t)(kc + slab * 8 + gr3) * 64 + ((gc7 ^ gr3) << 3), dK + slab * 512);
    }
#pragma unroll
    for (int i = 0; i < 4; i++) {
      int slab = wave * 4 + i;
      int row = slab * 4 + gr4;
      gload16(Vp + (size_t)row * SEQ + kc + ((gc15 ^ (row & 15)) << 3), dV + slab * 512);
    }
  };

  stage(0, 0);
  __syncthreads();  // drain prologue staging

  for (int t = 0; t < SEQ / 128; t++) {
    if (t < SEQ / 128 - 1) stage((t + 1) * 128, (t + 1) & 1);  // async prefetch
    const u16* cK = lK[t & 1];
    const u16* cV = lV[t & 1];

#pragma unroll
    for (int sub = 0; sub < 2; sub++) {
      const int ks = sub * 64;
      // S^T = K.Q^T : 4 key-mtiles x 32 q; K fragments read ONCE, feed both groups
      f32x4 sc[2][4];
#pragma unroll
      for (int mt = 0; mt < 4; mt++) {
        int row = ks + mt * 16 + l15;
        short8 kf0 = *(const short8*)&cK[row * 64 + ((quad ^ (row & 7)) << 3)];
        short8 kf1 = *(const short8*)&cK[row * 64 + (((4 + quad) ^ (row & 7)) << 3)];
#pragma unroll
        for (int g = 0; g < 2; g++) {
          f32x4 t0 = MFMA16(kf0, qf[g][0], zero);
          sc[g][mt] = MFMA16(kf1, qf[g][1], t0);
        }
      }
      // exp2 in place (truncating bf16 pack below, same numerics as before)
#pragma unroll
      for (int g = 0; g < 2; g++)
#pragma unroll
        for (int mt = 0; mt < 4; mt++)
#pragma unroll
          for (int r = 0; r < 4; r++) sc[g][mt][r] = __builtin_amdgcn_exp2f(sc[g][mt][r]);

      // PV: P routed in registers via cvt + permlane swaps; O^T += V^T.P^T ; l += ones.P^T
#pragma unroll
      for (int kbp = 0; kbp < 2; kbp++) {
        short8 pf[2];
#pragma unroll
        for (int g = 0; g < 2; g++) {
          u32 U0 = pack2t(sc[g][2 * kbp][0], sc[g][2 * kbp][1]);
          u32 W0 = pack2t(sc[g][2 * kbp + 1][0], sc[g][2 * kbp + 1][1]);
          u32 U1 = pack2t(sc[g][2 * kbp][2], sc[g][2 * kbp][3]);
          u32 W1 = pack2t(sc[g][2 * kbp + 1][2], sc[g][2 * kbp + 1][3]);
          pswap32(U0, W0);
          pswap16(U0, W0);
          pswap32(U1, W1);
          pswap16(U1, W1);
          u32 w[4] = {U0, U1, W0, W1};  // F0..F3
          pf[g] = *(const short8*)w;
        }
        lacc[0] = MFMA16(ones8, pf[0], lacc[0]);
        lacc[1] = MFMA16(ones8, pf[1], lacc[1]);
#pragma unroll
        for (int n = 0; n < 4; n++) {
          int row = n * 16 + l15;
          int chv = sub * 8 + kbp * 4 + quad;
          short8 vf = *(const short8*)&cV[row * 128 + ((chv ^ (row & 15)) << 3)];
          acc[0][n] = MFMA16(vf, pf[0], acc[0][n]);
          acc[1][n] = MFMA16(vf, pf[1], acc[1][n]);
        }
      }
    }
    __syncthreads();  // all waves done with cur buffer; prefetch drained (vmcnt)
  }

  // epilogue: per group, lane q = q0+g*16+l15, d = n*16+quad*4+{0..3}
#pragma unroll
  for (int g = 0; g < 2; g++) {
    float lq = __shfl(lacc[g][0], l15);  // l(q) lives at quad0 reg0, lane l15
    float inv = __builtin_amdgcn_rcpf(lq);
    u16* base = ctx + ((size_t)(b * SEQ + q0 + g * 16 + l15)) * DM + h * 64;
#pragma unroll
    for (int n = 0; n < 4; n++) {
      uint2 o;
      o.x = pack2t(acc[g][n][0] * inv, acc[g][n][1] * inv);
      o.y = pack2t(acc[g][n][2] * inv, acc[g][n][3] * inv);
      *(uint2*)(base + n * 16 + quad * 4) = o;
    }
  }
}

extern "C" void kernel_launch(void* const* d_in, const int* in_sizes, int n_in,
                              void* d_out, int out_size, void* d_ws, size_t ws_size,
                              hipStream_t stream) {
  const float* query = (const float*)d_in[0];
  const float* key_in = (const float*)d_in[1];
  const float* value_in = (const float*)d_in[2];
  const float* Wq = (const float*)d_in[3];
  const float* bq = (const float*)d_in[4];
  const float* Wk = (const float*)d_in[5];
  const float* bk = (const float*)d_in[6];
  const float* Wv = (const float*)d_in[7];
  const float* bv = (const float*)d_in[8];
  const float* Wo = (const float*)d_in[9];
  const float* bo = (const float*)d_in[10];

  float* out = (float*)d_out;   // [B,S,DM]
  float* outK = out + 4194304;  // [B,KVH,S,64]
  float* outV = out + 5242880;  // [B,KVH,S,64]

  char* ws = (char*)d_ws;
  u16* WqT = (u16*)(ws);               // 2M   [1024,1024] bf16
  u16* WkT = (u16*)(ws + 2097152);     // 0.5M [256,1024]
  u16* WvT = (u16*)(ws + 2621440);     // 0.5M
  u16* WoT = (u16*)(ws + 3145728);     // 2M
  u16* qbf = (u16*)(ws + 5242880);     // 8M  Q bf16 [B,H,S,64], pre-scaled log2e/8
  u16* kbf = (u16*)(ws + 13631488);    // 2M  K bf16 [B,KVH,S,64]
  u16* vtb = (u16*)(ws + 15728640);    // 2M  V^T bf16 [B,KVH,64,S]
  u16* ctxb = (u16*)(ws + 17825792);   // 8M  ctx bf16 [B,S,DM]
  // high-water: 26,214,400 bytes

  const float qscale = 0.125f * 1.44269504088896340736f;  // fold log2(e) -> exp2 softmax

  k_tr<<<dim3(32, 32, 4), 256, 0, stream>>>(Wq, Wk, Wv, Wo, WqT, WkT, WvT, WoT);
  k_proj<<<dim3(768), 256, 0, stream>>>(query, key_in, value_in, WqT, WkT, WvT, bq, bk, bv,
                                        qbf, outK, kbf, outV, vtb, qscale);
  k_flash<<<dim3(16, 32), 256, 0, stream>>>(qbf, kbf, vtb, ctxb);
  k_out<<<dim3(512), 256, 0, stream>>>(ctxb, WoT, bo, out);
}